// Round 1
// baseline (1730.165 us; speedup 1.0000x reference)
//
#include <hip/hip_runtime.h>
#include <stdint.h>

#define RMS_EPS 1.1920929e-07f
#define EPS_LIN 1e-6f

typedef __attribute__((ext_vector_type(8))) short bf16x8;
typedef __attribute__((ext_vector_type(4))) float f32x4;

__device__ __forceinline__ unsigned short f2bf(float f) {
  union { float f; unsigned int u; } v; v.f = f;
  unsigned int r = v.u + 0x7fffu + ((v.u >> 16) & 1u);
  return (unsigned short)(r >> 16);
}
__device__ __forceinline__ float bf2f(unsigned short s) {
  union { unsigned int u; float f; } v; v.u = ((unsigned int)s) << 16;
  return v.f;
}

// ---------------- fp32 -> bf16 convert ----------------
__global__ __launch_bounds__(256) void k_f32_to_bf16(const float* __restrict__ src,
                                                     unsigned short* __restrict__ dst, int n) {
  int i = (blockIdx.x * 256 + threadIdx.x) * 4;
  if (i >= n) return;
  float4 v = *reinterpret_cast<const float4*>(src + i);
  ushort4 o = { f2bf(v.x), f2bf(v.y), f2bf(v.z), f2bf(v.w) };
  *reinterpret_cast<ushort4*>(dst + i) = o;
}

// ---------------- rope table: cos/sin (4096 x 32) ----------------
__global__ __launch_bounds__(256) void k_rope_table(float* __restrict__ cosT,
                                                    float* __restrict__ sinT) {
  int idx = blockIdx.x * 256 + threadIdx.x;
  if (idx >= 4096 * 32) return;
  int l = idx >> 5, i = idx & 31;
  float inv_freq = expf(-((float)(2 * i) / 64.0f) * logf(10000.0f));
  float ang = (float)l * inv_freq;
  cosT[idx] = cosf(ang);
  sinT[idx] = sinf(ang);
}

// ---------------- async global->LDS 16B stage ----------------
__device__ __forceinline__ void stage16(const unsigned short* g, unsigned short* lds_base,
                                        int lane) {
#if __has_builtin(__builtin_amdgcn_global_load_lds)
  __builtin_amdgcn_global_load_lds(
      (const __attribute__((address_space(1))) unsigned int*)g,
      (__attribute__((address_space(3))) unsigned int*)lds_base, 16, 0, 0);
#else
  *reinterpret_cast<uint4*>(lds_base + lane * 8) = *reinterpret_cast<const uint4*>(g);
#endif
}

// ---------------- bf16 GEMM C = A(MxK) * B(NxK)^T + bias ----------------
// mode 0: QKV gemm -> scatter q(bf16 row-major), k(bf16 row-major), v(bf16 BHLD)
// mode 1: out gemm -> pre (fp32 row-major)
__global__ __launch_bounds__(256) void k_gemm_bt(
    const unsigned short* __restrict__ A, const unsigned short* __restrict__ Bw,
    const float* __restrict__ bias, int M, int N, int K, int mode,
    unsigned short* __restrict__ qb, unsigned short* __restrict__ kb,
    unsigned short* __restrict__ vb, float* __restrict__ pre) {
  __shared__ unsigned short As[128 * 32];
  __shared__ unsigned short Bs[128 * 32];
  const int nt = N >> 7;
  const int bm = blockIdx.x / nt, bn = blockIdx.x % nt;
  const int m0 = bm << 7, n0 = bn << 7;
  const int t = threadIdx.x;
  const int wave = t >> 6, lane = t & 63;
  const int wr = wave >> 1, wc = wave & 1;
  const int lrow = lane >> 2, lcol = (lane & 3) * 8;

  const unsigned short* Ag0 = A + (size_t)(m0 + wave * 32 + lrow) * K + lcol;
  const unsigned short* Ag1 = Ag0 + (size_t)16 * K;
  const unsigned short* Bg0 = Bw + (size_t)(n0 + wave * 32 + lrow) * K + lcol;
  const unsigned short* Bg1 = Bg0 + (size_t)16 * K;
  unsigned short* Al0 = As + wave * 1024;
  unsigned short* Al1 = As + wave * 1024 + 512;
  unsigned short* Bl0 = Bs + wave * 1024;
  unsigned short* Bl1 = Bs + wave * 1024 + 512;

  f32x4 acc[4][4] = {};
  const int quad = lane >> 4, m16 = lane & 15;

  for (int k0 = 0; k0 < K; k0 += 32) {
    stage16(Ag0 + k0, Al0, lane);
    stage16(Ag1 + k0, Al1, lane);
    stage16(Bg0 + k0, Bl0, lane);
    stage16(Bg1 + k0, Bl1, lane);
    __syncthreads();
    bf16x8 fa[4], fb[4];
#pragma unroll
    for (int i = 0; i < 4; ++i)
      fa[i] = *reinterpret_cast<const bf16x8*>(As + (wr * 64 + i * 16 + m16) * 32 + quad * 8);
#pragma unroll
    for (int j = 0; j < 4; ++j)
      fb[j] = *reinterpret_cast<const bf16x8*>(Bs + (wc * 64 + j * 16 + m16) * 32 + quad * 8);
#pragma unroll
    for (int i = 0; i < 4; ++i)
#pragma unroll
      for (int j = 0; j < 4; ++j)
        acc[i][j] = __builtin_amdgcn_mfma_f32_16x16x32_bf16(fa[i], fb[j], acc[i][j], 0, 0, 0);
    __syncthreads();
  }

#pragma unroll
  for (int i = 0; i < 4; ++i) {
    int rbase = m0 + wr * 64 + i * 16 + quad * 4;
#pragma unroll
    for (int j = 0; j < 4; ++j) {
      int col = n0 + wc * 64 + j * 16 + m16;
      float bc = bias[col];
#pragma unroll
      for (int r = 0; r < 4; ++r) {
        int row = rbase + r;
        float val = acc[i][j][r] + bc;
        if (mode == 0) {
          unsigned short bv = f2bf(val);
          if (col < 1024) {
            qb[(size_t)row * 1024 + col] = bv;
          } else if (col < 2048) {
            kb[(size_t)row * 1024 + (col - 1024)] = bv;
          } else {
            int h = (col - 2048) >> 6, d = col & 63;
            int b = row >> 12, l = row & 4095;
            vb[(((size_t)(b * 16 + h)) * 4096 + l) * 64 + d] = bv;
          }
        } else {
          pre[(size_t)row * N + col] = val;
        }
      }
    }
  }
}

// ---------------- q/k rmsnorm + rope + relu -> qf/kf (bf16 BHLD) ----------------
__global__ __launch_bounds__(256) void k_qknorm(
    const unsigned short* __restrict__ qb, const unsigned short* __restrict__ kb,
    const float* __restrict__ gq, const float* __restrict__ gk,
    const float* __restrict__ cosT, const float* __restrict__ sinT,
    unsigned short* __restrict__ qfb, unsigned short* __restrict__ kfb) {
  const int row = blockIdx.x;       // b*4096 + l
  const int l = row & 4095;
  const int b = row >> 12;
  const int t = threadIdx.x;
  __shared__ float red[4];
  __shared__ float s_sc;
  const int d = t * 4;
  const int h = d >> 6;
  const int i0 = (d & 63) >> 1;
  const float c0 = cosT[l * 32 + i0], s0 = sinT[l * 32 + i0];
  const float c1 = cosT[l * 32 + i0 + 1], s1 = sinT[l * 32 + i0 + 1];
  for (int which = 0; which < 2; ++which) {
    const unsigned short* src = which ? kb : qb;
    const float* g = which ? gk : gq;
    unsigned short* dst = which ? kfb : qfb;
    ushort4 u = *reinterpret_cast<const ushort4*>(src + (size_t)row * 1024 + d);
    float v0 = bf2f(u.x), v1 = bf2f(u.y), v2 = bf2f(u.z), v3 = bf2f(u.w);
    float ss = v0 * v0 + v1 * v1 + v2 * v2 + v3 * v3;
#pragma unroll
    for (int off = 32; off; off >>= 1) ss += __shfl_down(ss, off, 64);
    if ((t & 63) == 0) red[t >> 6] = ss;
    __syncthreads();
    if (t == 0)
      s_sc = rsqrtf((red[0] + red[1] + red[2] + red[3]) * (1.0f / 1024.0f) + RMS_EPS);
    __syncthreads();
    const float sc = s_sc;
    float x0 = v0 * sc * g[d], x1 = v1 * sc * g[d + 1];
    float x2 = v2 * sc * g[d + 2], x3 = v3 * sc * g[d + 3];
    float r0 = x0 * c0 - x1 * s0, r1 = x0 * s0 + x1 * c0;
    float r2 = x2 * c1 - x3 * s1, r3 = x2 * s1 + x3 * c1;
    ushort4 o = { f2bf(fmaxf(r0, 0.f)), f2bf(fmaxf(r1, 0.f)),
                  f2bf(fmaxf(r2, 0.f)), f2bf(fmaxf(r3, 0.f)) };
    *reinterpret_cast<ushort4*>(dst + (((size_t)(b * 16 + h)) * 4096 + l) * 64 + (d & 63)) = o;
    __syncthreads();
  }
}

// ---------------- vk[p][d] = sum_l vpad[l][p]*kf[l][d] (per bh) ----------------
__global__ __launch_bounds__(256) void k_vk(const unsigned short* __restrict__ vb,
                                            const unsigned short* __restrict__ kfb,
                                            float* __restrict__ vk) {
  const int bh = blockIdx.x >> 3;
  const int chunk = blockIdx.x & 7;
  const int t = threadIdx.x;
  const int wv = t >> 6, tx = t & 63;
  __shared__ float vt[64 * 64];
  __shared__ float kt[64 * 64];
  float acc[16] = {};
  float accD = 0.f;
  const int lb = chunk * 512;
  for (int tile = 0; tile < 8; ++tile) {
    const size_t rowbase = ((size_t)bh * 4096 + lb + tile * 64) * 64;
#pragma unroll
    for (int r = 0; r < 4; ++r) {
      int e = r * 1024 + t * 4;
      ushort4 uv = *reinterpret_cast<const ushort4*>(vb + rowbase + e);
      ushort4 uk = *reinterpret_cast<const ushort4*>(kfb + rowbase + e);
      float4 fv = { bf2f(uv.x), bf2f(uv.y), bf2f(uv.z), bf2f(uv.w) };
      float4 fk = { bf2f(uk.x), bf2f(uk.y), bf2f(uk.z), bf2f(uk.w) };
      *reinterpret_cast<float4*>(vt + e) = fv;
      *reinterpret_cast<float4*>(kt + e) = fk;
    }
    __syncthreads();
#pragma unroll 4
    for (int lp = 0; lp < 64; ++lp) {
      float kvv = kt[lp * 64 + tx];
      const float4* vr = reinterpret_cast<const float4*>(vt + lp * 64 + wv * 16);
      float4 v0 = vr[0], v1 = vr[1], v2 = vr[2], v3 = vr[3];
      acc[0] += v0.x * kvv;  acc[1] += v0.y * kvv;
      acc[2] += v0.z * kvv;  acc[3] += v0.w * kvv;
      acc[4] += v1.x * kvv;  acc[5] += v1.y * kvv;
      acc[6] += v1.z * kvv;  acc[7] += v1.w * kvv;
      acc[8] += v2.x * kvv;  acc[9] += v2.y * kvv;
      acc[10] += v2.z * kvv; acc[11] += v2.w * kvv;
      acc[12] += v3.x * kvv; acc[13] += v3.y * kvv;
      acc[14] += v3.z * kvv; acc[15] += v3.w * kvv;
      accD += kvv;
    }
    __syncthreads();
  }
  float* dst = vk + (size_t)bh * 65 * 64;
#pragma unroll
  for (int pp = 0; pp < 16; ++pp) atomicAdd(dst + (wv * 16 + pp) * 64 + tx, acc[pp]);
  if (wv == 0) atomicAdd(dst + 64 * 64 + tx, accD);
}

// ---------------- res = qf . vk^T ; attn = res[:64]/(res[64]+eps) -> bf16 BLD --------
__global__ __launch_bounds__(256) void k_res(const unsigned short* __restrict__ qfb,
                                             const float* __restrict__ vk,
                                             unsigned short* __restrict__ attnb) {
  const int bh = blockIdx.x >> 6;
  const int lt = (blockIdx.x & 63) << 6;
  const int b = bh >> 4, h = bh & 15;
  const int t = threadIdx.x;
  const int wv = t >> 6, lane = t & 63;
  __shared__ float vks[65 * 64];
  __shared__ float qs[64 * 65];   // +1 pad to kill bank conflicts
  __shared__ float den[64];
  const float* vsrc = vk + (size_t)bh * 65 * 64;
  for (int i = t; i < 65 * 64; i += 256) vks[i] = vsrc[i];
  const size_t qbase = ((size_t)bh * 4096 + lt) * 64;
#pragma unroll
  for (int r = 0; r < 4; ++r) {
    int e = r * 1024 + t * 4;
    int lr = e >> 6, cc = e & 63;
    ushort4 u = *reinterpret_cast<const ushort4*>(qfb + qbase + e);
    float* q = qs + lr * 65 + cc;
    q[0] = bf2f(u.x); q[1] = bf2f(u.y); q[2] = bf2f(u.z); q[3] = bf2f(u.w);
  }
  __syncthreads();
  float qreg[64];
#pragma unroll
  for (int d2 = 0; d2 < 64; ++d2) qreg[d2] = qs[lane * 65 + d2];
  float res[16];
#pragma unroll
  for (int pp = 0; pp < 16; ++pp) {
    const float4* vr = reinterpret_cast<const float4*>(vks + (wv * 16 + pp) * 64);
    float s = 0.f;
#pragma unroll
    for (int d4 = 0; d4 < 16; ++d4) {
      float4 vv = vr[d4];
      s += vv.x * qreg[d4 * 4] + vv.y * qreg[d4 * 4 + 1] +
           vv.z * qreg[d4 * 4 + 2] + vv.w * qreg[d4 * 4 + 3];
    }
    res[pp] = s;
  }
  if (wv == 0) {
    const float4* vr = reinterpret_cast<const float4*>(vks + 64 * 64);
    float s = 0.f;
#pragma unroll
    for (int d4 = 0; d4 < 16; ++d4) {
      float4 vv = vr[d4];
      s += vv.x * qreg[d4 * 4] + vv.y * qreg[d4 * 4 + 1] +
           vv.z * qreg[d4 * 4 + 2] + vv.w * qreg[d4 * 4 + 3];
    }
    den[lane] = s;
  }
  __syncthreads();
  const float inv = 1.0f / (den[lane] + EPS_LIN);
  unsigned short* dst = attnb + ((size_t)(b * 4096 + lt + lane)) * 1024 + h * 64 + wv * 16;
#pragma unroll
  for (int g4 = 0; g4 < 4; ++g4) {
    ushort4 o = { f2bf(res[g4 * 4] * inv), f2bf(res[g4 * 4 + 1] * inv),
                  f2bf(res[g4 * 4 + 2] * inv), f2bf(res[g4 * 4 + 3] * inv) };
    reinterpret_cast<ushort4*>(dst)[g4] = o;
  }
}

// ---------------- final rmsnorm ----------------
__global__ __launch_bounds__(256) void k_outnorm(const float* __restrict__ pre,
                                                 const float* __restrict__ gout,
                                                 float* __restrict__ out) {
  const int row = blockIdx.x;
  const int t = threadIdx.x;
  __shared__ float red[4];
  __shared__ float s_sc;
  float4 v = *reinterpret_cast<const float4*>(pre + (size_t)row * 1024 + t * 4);
  float ss = v.x * v.x + v.y * v.y + v.z * v.z + v.w * v.w;
#pragma unroll
  for (int off = 32; off; off >>= 1) ss += __shfl_down(ss, off, 64);
  if ((t & 63) == 0) red[t >> 6] = ss;
  __syncthreads();
  if (t == 0) s_sc = rsqrtf((red[0] + red[1] + red[2] + red[3]) * (1.0f / 1024.0f) + RMS_EPS);
  __syncthreads();
  const float sc = s_sc;
  const int d = t * 4;
  float4 o = { v.x * sc * gout[d], v.y * sc * gout[d + 1],
               v.z * sc * gout[d + 2], v.w * sc * gout[d + 3] };
  *reinterpret_cast<float4*>(out + (size_t)row * 1024 + d) = o;
}

// ---------------- workspace layout (bytes) ----------------
#define OFF_XB     0ull
#define OFF_WQKVB  33554432ull
#define OFF_WOUTB  39845888ull
#define OFF_QB     41943040ull
#define OFF_KB     75497472ull
#define OFF_VB     109051904ull
#define OFF_QFB    142606336ull
#define OFF_KFB    176160768ull
#define OFF_VK     209715200ull
#define OFF_ATTNB  210780160ull
#define OFF_COST   244334592ull
#define OFF_SINT   244858880ull
#define WS_NEEDED  245383168ull
// pre (fp32, 64MB) aliases OFF_QB..OFF_VB (qb/kb dead by then)

extern "C" void kernel_launch(void* const* d_in, const int* in_sizes, int n_in,
                              void* d_out, int out_size, void* d_ws, size_t ws_size,
                              hipStream_t stream) {
  const float* x    = (const float*)d_in[0];
  const float* Wqkv = (const float*)d_in[1];
  const float* bqkv = (const float*)d_in[2];
  const float* gq   = (const float*)d_in[3];
  const float* gk   = (const float*)d_in[4];
  const float* Wout = (const float*)d_in[5];
  const float* bout = (const float*)d_in[6];
  const float* gout = (const float*)d_in[7];

  if (ws_size < WS_NEEDED) return;  // workspace too small — visible as stub-like absmax

  char* ws = (char*)d_ws;
  unsigned short* xb    = (unsigned short*)(ws + OFF_XB);
  unsigned short* wqkvb = (unsigned short*)(ws + OFF_WQKVB);
  unsigned short* woutb = (unsigned short*)(ws + OFF_WOUTB);
  unsigned short* qb    = (unsigned short*)(ws + OFF_QB);
  unsigned short* kb    = (unsigned short*)(ws + OFF_KB);
  unsigned short* vb    = (unsigned short*)(ws + OFF_VB);
  unsigned short* qfb   = (unsigned short*)(ws + OFF_QFB);
  unsigned short* kfb   = (unsigned short*)(ws + OFF_KFB);
  float*          vkbuf = (float*)(ws + OFF_VK);
  unsigned short* attnb = (unsigned short*)(ws + OFF_ATTNB);
  float*          cosT  = (float*)(ws + OFF_COST);
  float*          sinT  = (float*)(ws + OFF_SINT);
  float*          pre   = (float*)(ws + OFF_QB);  // alias

  k_f32_to_bf16<<<16384, 256, 0, stream>>>(x, xb, 16777216);
  k_f32_to_bf16<<<3072, 256, 0, stream>>>(Wqkv, wqkvb, 3145728);
  k_f32_to_bf16<<<1024, 256, 0, stream>>>(Wout, woutb, 1048576);
  k_rope_table<<<512, 256, 0, stream>>>(cosT, sinT);

  // QKV gemm: M=16384 N=3072 K=1024
  k_gemm_bt<<<128 * 24, 256, 0, stream>>>(xb, wqkvb, bqkv, 16384, 3072, 1024, 0,
                                          qb, kb, vb, nullptr);
  k_qknorm<<<16384, 256, 0, stream>>>(qb, kb, gq, gk, cosT, sinT, qfb, kfb);

  hipMemsetAsync(vkbuf, 0, 64 * 65 * 64 * sizeof(float), stream);
  k_vk<<<512, 256, 0, stream>>>(vb, kfb, vkbuf);
  k_res<<<4096, 256, 0, stream>>>(qfb, vkbuf, attnb);

  // out gemm: M=16384 N=1024 K=1024 -> pre (aliases qb/kb region)
  k_gemm_bt<<<128 * 8, 256, 0, stream>>>(attnb, woutb, bout, 16384, 1024, 1024, 1,
                                         nullptr, nullptr, nullptr, pre);
  k_outnorm<<<16384, 256, 0, stream>>>(pre, gout, (float*)d_out);
}

// Round 2
// 496.959 us; speedup vs baseline: 3.4815x; 3.4815x over previous
//
#include <hip/hip_runtime.h>
#include <stdint.h>

#define RMS_EPS 1.1920929e-07f
#define EPS_LIN 1e-6f

typedef __attribute__((ext_vector_type(8))) short bf16x8;
typedef __attribute__((ext_vector_type(4))) float f32x4;

__device__ __forceinline__ unsigned short f2bf(float f) {
  union { float f; unsigned int u; } v; v.f = f;
  unsigned int r = v.u + 0x7fffu + ((v.u >> 16) & 1u);
  return (unsigned short)(r >> 16);
}
__device__ __forceinline__ float bf2f(unsigned short s) {
  union { unsigned int u; float f; } v; v.u = ((unsigned int)s) << 16;
  return v.f;
}

// ---------------- fp32 -> bf16 convert ----------------
__global__ __launch_bounds__(256) void k_f32_to_bf16(const float* __restrict__ src,
                                                     unsigned short* __restrict__ dst, int n) {
  int i = (blockIdx.x * 256 + threadIdx.x) * 4;
  if (i >= n) return;
  float4 v = *reinterpret_cast<const float4*>(src + i);
  ushort4 o = { f2bf(v.x), f2bf(v.y), f2bf(v.z), f2bf(v.w) };
  *reinterpret_cast<ushort4*>(dst + i) = o;
}

// ---------------- rope table: cos/sin (4096 x 32) ----------------
__global__ __launch_bounds__(256) void k_rope_table(float* __restrict__ cosT,
                                                    float* __restrict__ sinT) {
  int idx = blockIdx.x * 256 + threadIdx.x;
  if (idx >= 4096 * 32) return;
  int l = idx >> 5, i = idx & 31;
  float inv_freq = expf(-((float)(2 * i) / 64.0f) * logf(10000.0f));
  float ang = (float)l * inv_freq;
  cosT[idx] = cosf(ang);
  sinT[idx] = sinf(ang);
}

// ---------------- async global->LDS 16B stage ----------------
__device__ __forceinline__ void stage16(const unsigned short* g, unsigned short* lds_base,
                                        int lane) {
#if __has_builtin(__builtin_amdgcn_global_load_lds)
  __builtin_amdgcn_global_load_lds(
      (const __attribute__((address_space(1))) unsigned int*)g,
      (__attribute__((address_space(3))) unsigned int*)lds_base, 16, 0, 0);
#else
  *reinterpret_cast<uint4*>(lds_base + lane * 8) = *reinterpret_cast<const uint4*>(g);
#endif
}

// ---------------- bf16 GEMM C = A(MxK) * B(NxK)^T + bias ----------------
// mode 0: QKV gemm -> scatter q(bf16 row-major), k(bf16 row-major), v(bf16 BHLD)
// mode 1: out gemm -> pre (fp32 row-major)
__global__ __launch_bounds__(256) void k_gemm_bt(
    const unsigned short* __restrict__ A, const unsigned short* __restrict__ Bw,
    const float* __restrict__ bias, int M, int N, int K, int mode,
    unsigned short* __restrict__ qb, unsigned short* __restrict__ kb,
    unsigned short* __restrict__ vb, float* __restrict__ pre) {
  __shared__ unsigned short As[128 * 32];
  __shared__ unsigned short Bs[128 * 32];
  const int nt = N >> 7;
  const int bm = blockIdx.x / nt, bn = blockIdx.x % nt;
  const int m0 = bm << 7, n0 = bn << 7;
  const int t = threadIdx.x;
  const int wave = t >> 6, lane = t & 63;
  const int wr = wave >> 1, wc = wave & 1;
  const int lrow = lane >> 2, lcol = (lane & 3) * 8;

  const unsigned short* Ag0 = A + (size_t)(m0 + wave * 32 + lrow) * K + lcol;
  const unsigned short* Ag1 = Ag0 + (size_t)16 * K;
  const unsigned short* Bg0 = Bw + (size_t)(n0 + wave * 32 + lrow) * K + lcol;
  const unsigned short* Bg1 = Bg0 + (size_t)16 * K;
  unsigned short* Al0 = As + wave * 1024;
  unsigned short* Al1 = As + wave * 1024 + 512;
  unsigned short* Bl0 = Bs + wave * 1024;
  unsigned short* Bl1 = Bs + wave * 1024 + 512;

  f32x4 acc[4][4] = {};
  const int quad = lane >> 4, m16 = lane & 15;

  for (int k0 = 0; k0 < K; k0 += 32) {
    stage16(Ag0 + k0, Al0, lane);
    stage16(Ag1 + k0, Al1, lane);
    stage16(Bg0 + k0, Bl0, lane);
    stage16(Bg1 + k0, Bl1, lane);
    __syncthreads();
    bf16x8 fa[4], fb[4];
#pragma unroll
    for (int i = 0; i < 4; ++i)
      fa[i] = *reinterpret_cast<const bf16x8*>(As + (wr * 64 + i * 16 + m16) * 32 + quad * 8);
#pragma unroll
    for (int j = 0; j < 4; ++j)
      fb[j] = *reinterpret_cast<const bf16x8*>(Bs + (wc * 64 + j * 16 + m16) * 32 + quad * 8);
#pragma unroll
    for (int i = 0; i < 4; ++i)
#pragma unroll
      for (int j = 0; j < 4; ++j)
        acc[i][j] = __builtin_amdgcn_mfma_f32_16x16x32_bf16(fa[i], fb[j], acc[i][j], 0, 0, 0);
    __syncthreads();
  }

#pragma unroll
  for (int i = 0; i < 4; ++i) {
    int rbase = m0 + wr * 64 + i * 16 + quad * 4;
#pragma unroll
    for (int j = 0; j < 4; ++j) {
      int col = n0 + wc * 64 + j * 16 + m16;
      float bc = bias[col];
#pragma unroll
      for (int r = 0; r < 4; ++r) {
        int row = rbase + r;
        float val = acc[i][j][r] + bc;
        if (mode == 0) {
          unsigned short bv = f2bf(val);
          if (col < 1024) {
            qb[(size_t)row * 1024 + col] = bv;
          } else if (col < 2048) {
            kb[(size_t)row * 1024 + (col - 1024)] = bv;
          } else {
            int h = (col - 2048) >> 6, d = col & 63;
            int b = row >> 12, l = row & 4095;
            vb[(((size_t)(b * 16 + h)) * 4096 + l) * 64 + d] = bv;
          }
        } else {
          pre[(size_t)row * N + col] = val;
        }
      }
    }
  }
}

// ---------------- q/k rmsnorm + rope + relu -> qf/kf (bf16 BHLD) ----------------
__global__ __launch_bounds__(256) void k_qknorm(
    const unsigned short* __restrict__ qb, const unsigned short* __restrict__ kb,
    const float* __restrict__ gq, const float* __restrict__ gk,
    const float* __restrict__ cosT, const float* __restrict__ sinT,
    unsigned short* __restrict__ qfb, unsigned short* __restrict__ kfb) {
  const int row = blockIdx.x;       // b*4096 + l
  const int l = row & 4095;
  const int b = row >> 12;
  const int t = threadIdx.x;
  __shared__ float red[4];
  __shared__ float s_sc;
  const int d = t * 4;
  const int h = d >> 6;
  const int i0 = (d & 63) >> 1;
  const float c0 = cosT[l * 32 + i0], s0 = sinT[l * 32 + i0];
  const float c1 = cosT[l * 32 + i0 + 1], s1 = sinT[l * 32 + i0 + 1];
  for (int which = 0; which < 2; ++which) {
    const unsigned short* src = which ? kb : qb;
    const float* g = which ? gk : gq;
    unsigned short* dst = which ? kfb : qfb;
    ushort4 u = *reinterpret_cast<const ushort4*>(src + (size_t)row * 1024 + d);
    float v0 = bf2f(u.x), v1 = bf2f(u.y), v2 = bf2f(u.z), v3 = bf2f(u.w);
    float ss = v0 * v0 + v1 * v1 + v2 * v2 + v3 * v3;
#pragma unroll
    for (int off = 32; off; off >>= 1) ss += __shfl_down(ss, off, 64);
    if ((t & 63) == 0) red[t >> 6] = ss;
    __syncthreads();
    if (t == 0)
      s_sc = rsqrtf((red[0] + red[1] + red[2] + red[3]) * (1.0f / 1024.0f) + RMS_EPS);
    __syncthreads();
    const float sc = s_sc;
    float x0 = v0 * sc * g[d], x1 = v1 * sc * g[d + 1];
    float x2 = v2 * sc * g[d + 2], x3 = v3 * sc * g[d + 3];
    float r0 = x0 * c0 - x1 * s0, r1 = x0 * s0 + x1 * c0;
    float r2 = x2 * c1 - x3 * s1, r3 = x2 * s1 + x3 * c1;
    ushort4 o = { f2bf(fmaxf(r0, 0.f)), f2bf(fmaxf(r1, 0.f)),
                  f2bf(fmaxf(r2, 0.f)), f2bf(fmaxf(r3, 0.f)) };
    *reinterpret_cast<ushort4*>(dst + (((size_t)(b * 16 + h)) * 4096 + l) * 64 + (d & 63)) = o;
    __syncthreads();
  }
}

// ---------------- vk[p][d] = sum_l vpad[l][p]*kf[l][d] (per bh) ----------------
__global__ __launch_bounds__(256) void k_vk(const unsigned short* __restrict__ vb,
                                            const unsigned short* __restrict__ kfb,
                                            float* __restrict__ vk) {
  const int bh = blockIdx.x >> 3;
  const int chunk = blockIdx.x & 7;
  const int t = threadIdx.x;
  const int wv = t >> 6, tx = t & 63;
  __shared__ float vt[64 * 64];
  __shared__ float kt[64 * 64];
  float acc[16] = {};
  float accD = 0.f;
  const int lb = chunk * 512;
  for (int tile = 0; tile < 8; ++tile) {
    const size_t rowbase = ((size_t)bh * 4096 + lb + tile * 64) * 64;
#pragma unroll
    for (int r = 0; r < 4; ++r) {
      int e = r * 1024 + t * 4;
      ushort4 uv = *reinterpret_cast<const ushort4*>(vb + rowbase + e);
      ushort4 uk = *reinterpret_cast<const ushort4*>(kfb + rowbase + e);
      float4 fv = { bf2f(uv.x), bf2f(uv.y), bf2f(uv.z), bf2f(uv.w) };
      float4 fk = { bf2f(uk.x), bf2f(uk.y), bf2f(uk.z), bf2f(uk.w) };
      *reinterpret_cast<float4*>(vt + e) = fv;
      *reinterpret_cast<float4*>(kt + e) = fk;
    }
    __syncthreads();
#pragma unroll 4
    for (int lp = 0; lp < 64; ++lp) {
      float kvv = kt[lp * 64 + tx];
      const float4* vr = reinterpret_cast<const float4*>(vt + lp * 64 + wv * 16);
      float4 v0 = vr[0], v1 = vr[1], v2 = vr[2], v3 = vr[3];
      acc[0] += v0.x * kvv;  acc[1] += v0.y * kvv;
      acc[2] += v0.z * kvv;  acc[3] += v0.w * kvv;
      acc[4] += v1.x * kvv;  acc[5] += v1.y * kvv;
      acc[6] += v1.z * kvv;  acc[7] += v1.w * kvv;
      acc[8] += v2.x * kvv;  acc[9] += v2.y * kvv;
      acc[10] += v2.z * kvv; acc[11] += v2.w * kvv;
      acc[12] += v3.x * kvv; acc[13] += v3.y * kvv;
      acc[14] += v3.z * kvv; acc[15] += v3.w * kvv;
      accD += kvv;
    }
    __syncthreads();
  }
  float* dst = vk + (size_t)bh * 65 * 64;
#pragma unroll
  for (int pp = 0; pp < 16; ++pp) atomicAdd(dst + (wv * 16 + pp) * 64 + tx, acc[pp]);
  if (wv == 0) atomicAdd(dst + 64 * 64 + tx, accD);
}

// ---------------- res = qf . vk^T ; attn = res[:64]/(res[64]+eps) -> bf16 BLD --------
// Rewritten R2: no qreg[64] (was spilling at VGPR=256 -> 3.9GB scratch traffic).
// d4-major loop: q float4 per-lane from padded LDS, vks reads lane-invariant
// (broadcast, conflict-free). Output staged in LDS, stored as full 64B lines.
__global__ __launch_bounds__(256) void k_res(const unsigned short* __restrict__ qfb,
                                             const float* __restrict__ vk,
                                             unsigned short* __restrict__ attnb) {
  const int bh = blockIdx.x >> 6;
  const int lt = (blockIdx.x & 63) << 6;
  const int b = bh >> 4, h = bh & 15;
  const int t = threadIdx.x;
  const int wv = t >> 6, lane = t & 63;
  __shared__ float vks[65 * 64];
  __shared__ float qs[64 * 68];   // stride 68 floats: 16B-aligned rows, padded
  const float* vsrc = vk + (size_t)bh * 65 * 64;
  for (int i = t; i < 65 * 64; i += 256) vks[i] = vsrc[i];
  const size_t qbase = ((size_t)bh * 4096 + lt) * 64;
#pragma unroll
  for (int r = 0; r < 4; ++r) {
    int e = r * 1024 + t * 4;
    int lr = e >> 6, cc = e & 63;
    ushort4 u = *reinterpret_cast<const ushort4*>(qfb + qbase + e);
    float4 f = { bf2f(u.x), bf2f(u.y), bf2f(u.z), bf2f(u.w) };
    *reinterpret_cast<float4*>(qs + lr * 68 + cc) = f;
  }
  __syncthreads();
  float res[16] = {};
  float den = 0.f;
  const float4* qrow = reinterpret_cast<const float4*>(qs + lane * 68);
  const float4* vrow = reinterpret_cast<const float4*>(vks);
#pragma unroll
  for (int d4 = 0; d4 < 16; ++d4) {
    float4 q = qrow[d4];
#pragma unroll
    for (int pp = 0; pp < 16; ++pp) {
      float4 vv = vrow[(wv * 16 + pp) * 16 + d4];   // lane-invariant -> broadcast
      res[pp] += vv.x * q.x + vv.y * q.y + vv.z * q.z + vv.w * q.w;
    }
    float4 vd = vrow[64 * 16 + d4];
    den += vd.x * q.x + vd.y * q.y + vd.z * q.z + vd.w * q.w;
  }
  const float inv = 1.0f / (den + EPS_LIN);
  __syncthreads();
  // stage 64x64 bf16 tile in LDS (reuse vks region)
  unsigned short* tile = reinterpret_cast<unsigned short*>(vks);
#pragma unroll
  for (int g4 = 0; g4 < 4; ++g4) {
    ushort4 o = { f2bf(res[g4 * 4] * inv), f2bf(res[g4 * 4 + 1] * inv),
                  f2bf(res[g4 * 4 + 2] * inv), f2bf(res[g4 * 4 + 3] * inv) };
    *reinterpret_cast<ushort4*>(tile + lane * 64 + wv * 16 + g4 * 4) = o;
  }
  __syncthreads();
  // coalesced store: 4 consecutive lanes cover one full 64B line
  const int row = t >> 2;
  unsigned short* dst = attnb + ((size_t)(b * 4096 + lt + row)) * 1024 + h * 64;
#pragma unroll
  for (int g = 0; g < 2; ++g) {
    int el = (t & 3) * 8 + g * 32;
    uint4 pix = *reinterpret_cast<const uint4*>(tile + row * 64 + el);
    *reinterpret_cast<uint4*>(dst + el) = pix;
  }
}

// ---------------- final rmsnorm ----------------
__global__ __launch_bounds__(256) void k_outnorm(const float* __restrict__ pre,
                                                 const float* __restrict__ gout,
                                                 float* __restrict__ out) {
  const int row = blockIdx.x;
  const int t = threadIdx.x;
  __shared__ float red[4];
  __shared__ float s_sc;
  float4 v = *reinterpret_cast<const float4*>(pre + (size_t)row * 1024 + t * 4);
  float ss = v.x * v.x + v.y * v.y + v.z * v.z + v.w * v.w;
#pragma unroll
  for (int off = 32; off; off >>= 1) ss += __shfl_down(ss, off, 64);
  if ((t & 63) == 0) red[t >> 6] = ss;
  __syncthreads();
  if (t == 0) s_sc = rsqrtf((red[0] + red[1] + red[2] + red[3]) * (1.0f / 1024.0f) + RMS_EPS);
  __syncthreads();
  const float sc = s_sc;
  const int d = t * 4;
  float4 o = { v.x * sc * gout[d], v.y * sc * gout[d + 1],
               v.z * sc * gout[d + 2], v.w * sc * gout[d + 3] };
  *reinterpret_cast<float4*>(out + (size_t)row * 1024 + d) = o;
}

// ---------------- workspace layout (bytes) ----------------
#define OFF_XB     0ull
#define OFF_WQKVB  33554432ull
#define OFF_WOUTB  39845888ull
#define OFF_QB     41943040ull
#define OFF_KB     75497472ull
#define OFF_VB     109051904ull
#define OFF_QFB    142606336ull
#define OFF_KFB    176160768ull
#define OFF_VK     209715200ull
#define OFF_ATTNB  210780160ull
#define OFF_COST   244334592ull
#define OFF_SINT   244858880ull
#define WS_NEEDED  245383168ull
// pre (fp32, 64MB) aliases OFF_QB..OFF_VB (qb/kb dead by then)

extern "C" void kernel_launch(void* const* d_in, const int* in_sizes, int n_in,
                              void* d_out, int out_size, void* d_ws, size_t ws_size,
                              hipStream_t stream) {
  const float* x    = (const float*)d_in[0];
  const float* Wqkv = (const float*)d_in[1];
  const float* bqkv = (const float*)d_in[2];
  const float* gq   = (const float*)d_in[3];
  const float* gk   = (const float*)d_in[4];
  const float* Wout = (const float*)d_in[5];
  const float* bout = (const float*)d_in[6];
  const float* gout = (const float*)d_in[7];

  if (ws_size < WS_NEEDED) return;

  char* ws = (char*)d_ws;
  unsigned short* xb    = (unsigned short*)(ws + OFF_XB);
  unsigned short* wqkvb = (unsigned short*)(ws + OFF_WQKVB);
  unsigned short* woutb = (unsigned short*)(ws + OFF_WOUTB);
  unsigned short* qb    = (unsigned short*)(ws + OFF_QB);
  unsigned short* kb    = (unsigned short*)(ws + OFF_KB);
  unsigned short* vb    = (unsigned short*)(ws + OFF_VB);
  unsigned short* qfb   = (unsigned short*)(ws + OFF_QFB);
  unsigned short* kfb   = (unsigned short*)(ws + OFF_KFB);
  float*          vkbuf = (float*)(ws + OFF_VK);
  unsigned short* attnb = (unsigned short*)(ws + OFF_ATTNB);
  float*          cosT  = (float*)(ws + OFF_COST);
  float*          sinT  = (float*)(ws + OFF_SINT);
  float*          pre   = (float*)(ws + OFF_QB);  // alias

  k_f32_to_bf16<<<16384, 256, 0, stream>>>(x, xb, 16777216);
  k_f32_to_bf16<<<3072, 256, 0, stream>>>(Wqkv, wqkvb, 3145728);
  k_f32_to_bf16<<<1024, 256, 0, stream>>>(Wout, woutb, 1048576);
  k_rope_table<<<512, 256, 0, stream>>>(cosT, sinT);

  // QKV gemm: M=16384 N=3072 K=1024
  k_gemm_bt<<<128 * 24, 256, 0, stream>>>(xb, wqkvb, bqkv, 16384, 3072, 1024, 0,
                                          qb, kb, vb, nullptr);
  k_qknorm<<<16384, 256, 0, stream>>>(qb, kb, gq, gk, cosT, sinT, qfb, kfb);

  hipMemsetAsync(vkbuf, 0, 64 * 65 * 64 * sizeof(float), stream);
  k_vk<<<512, 256, 0, stream>>>(vb, kfb, vkbuf);
  k_res<<<4096, 256, 0, stream>>>(qfb, vkbuf, attnb);

  // out gemm: M=16384 N=1024 K=1024 -> pre (aliases qb/kb region)
  k_gemm_bt<<<128 * 8, 256, 0, stream>>>(attnb, woutb, bout, 16384, 1024, 1024, 1,
                                         nullptr, nullptr, nullptr, pre);
  k_outnorm<<<16384, 256, 0, stream>>>(pre, gout, (float*)d_out);
}

// Round 3
// 459.899 us; speedup vs baseline: 3.7621x; 1.0806x over previous
//
#include <hip/hip_runtime.h>
#include <stdint.h>

#define RMS_EPS 1.1920929e-07f
#define EPS_LIN 1e-6f

typedef __attribute__((ext_vector_type(8))) short bf16x8;
typedef __attribute__((ext_vector_type(4))) float f32x4;

__device__ __forceinline__ unsigned short f2bf(float f) {
  union { float f; unsigned int u; } v; v.f = f;
  unsigned int r = v.u + 0x7fffu + ((v.u >> 16) & 1u);
  return (unsigned short)(r >> 16);
}
__device__ __forceinline__ float bf2f(unsigned short s) {
  union { unsigned int u; float f; } v; v.u = ((unsigned int)s) << 16;
  return v.f;
}

// ---------------- fp32 -> bf16 convert ----------------
__global__ __launch_bounds__(256) void k_f32_to_bf16(const float* __restrict__ src,
                                                     unsigned short* __restrict__ dst, int n) {
  int i = (blockIdx.x * 256 + threadIdx.x) * 4;
  if (i >= n) return;
  float4 v = *reinterpret_cast<const float4*>(src + i);
  ushort4 o = { f2bf(v.x), f2bf(v.y), f2bf(v.z), f2bf(v.w) };
  *reinterpret_cast<ushort4*>(dst + i) = o;
}

// ---------------- rope table: cos/sin (4096 x 32) ----------------
__global__ __launch_bounds__(256) void k_rope_table(float* __restrict__ cosT,
                                                    float* __restrict__ sinT) {
  int idx = blockIdx.x * 256 + threadIdx.x;
  if (idx >= 4096 * 32) return;
  int l = idx >> 5, i = idx & 31;
  float inv_freq = expf(-((float)(2 * i) / 64.0f) * logf(10000.0f));
  float ang = (float)l * inv_freq;
  cosT[idx] = cosf(ang);
  sinT[idx] = sinf(ang);
}

// ---------------- async global->LDS 16B stage ----------------
__device__ __forceinline__ void stage16(const unsigned short* g, unsigned short* lds_base,
                                        int lane) {
#if __has_builtin(__builtin_amdgcn_global_load_lds)
  __builtin_amdgcn_global_load_lds(
      (const __attribute__((address_space(1))) unsigned int*)g,
      (__attribute__((address_space(3))) unsigned int*)lds_base, 16, 0, 0);
#else
  *reinterpret_cast<uint4*>(lds_base + lane * 8) = *reinterpret_cast<const uint4*>(g);
#endif
}

// ---------------- bf16 GEMM C = A(MxK) * B(NxK)^T + bias ----------------
// mode 0: QKV gemm -> scatter q(bf16 row-major), k(bf16 row-major), v(bf16 BHLD)
// mode 1: out gemm -> preb (bf16 row-major)
__global__ __launch_bounds__(256) void k_gemm_bt(
    const unsigned short* __restrict__ A, const unsigned short* __restrict__ Bw,
    const float* __restrict__ bias, int M, int N, int K, int mode,
    unsigned short* __restrict__ qb, unsigned short* __restrict__ kb,
    unsigned short* __restrict__ vb, unsigned short* __restrict__ preb) {
  __shared__ unsigned short As[128 * 32];
  __shared__ unsigned short Bs[128 * 32];
  const int nt = N >> 7;
  const int bm = blockIdx.x / nt, bn = blockIdx.x % nt;
  const int m0 = bm << 7, n0 = bn << 7;
  const int t = threadIdx.x;
  const int wave = t >> 6, lane = t & 63;
  const int wr = wave >> 1, wc = wave & 1;
  const int lrow = lane >> 2, lcol = (lane & 3) * 8;

  const unsigned short* Ag0 = A + (size_t)(m0 + wave * 32 + lrow) * K + lcol;
  const unsigned short* Ag1 = Ag0 + (size_t)16 * K;
  const unsigned short* Bg0 = Bw + (size_t)(n0 + wave * 32 + lrow) * K + lcol;
  const unsigned short* Bg1 = Bg0 + (size_t)16 * K;
  unsigned short* Al0 = As + wave * 1024;
  unsigned short* Al1 = As + wave * 1024 + 512;
  unsigned short* Bl0 = Bs + wave * 1024;
  unsigned short* Bl1 = Bs + wave * 1024 + 512;

  f32x4 acc[4][4] = {};
  const int quad = lane >> 4, m16 = lane & 15;

  for (int k0 = 0; k0 < K; k0 += 32) {
    stage16(Ag0 + k0, Al0, lane);
    stage16(Ag1 + k0, Al1, lane);
    stage16(Bg0 + k0, Bl0, lane);
    stage16(Bg1 + k0, Bl1, lane);
    __syncthreads();
    bf16x8 fa[4], fb[4];
#pragma unroll
    for (int i = 0; i < 4; ++i)
      fa[i] = *reinterpret_cast<const bf16x8*>(As + (wr * 64 + i * 16 + m16) * 32 + quad * 8);
#pragma unroll
    for (int j = 0; j < 4; ++j)
      fb[j] = *reinterpret_cast<const bf16x8*>(Bs + (wc * 64 + j * 16 + m16) * 32 + quad * 8);
#pragma unroll
    for (int i = 0; i < 4; ++i)
#pragma unroll
      for (int j = 0; j < 4; ++j)
        acc[i][j] = __builtin_amdgcn_mfma_f32_16x16x32_bf16(fa[i], fb[j], acc[i][j], 0, 0, 0);
    __syncthreads();
  }

#pragma unroll
  for (int i = 0; i < 4; ++i) {
    int rbase = m0 + wr * 64 + i * 16 + quad * 4;
#pragma unroll
    for (int j = 0; j < 4; ++j) {
      int col = n0 + wc * 64 + j * 16 + m16;
      float bc = bias[col];
#pragma unroll
      for (int r = 0; r < 4; ++r) {
        int row = rbase + r;
        float val = acc[i][j][r] + bc;
        unsigned short bv = f2bf(val);
        if (mode == 0) {
          if (col < 1024) {
            qb[(size_t)row * 1024 + col] = bv;
          } else if (col < 2048) {
            kb[(size_t)row * 1024 + (col - 1024)] = bv;
          } else {
            int h = (col - 2048) >> 6, d = col & 63;
            int b = row >> 12, l = row & 4095;
            vb[(((size_t)(b * 16 + h)) * 4096 + l) * 64 + d] = bv;
          }
        } else {
          preb[(size_t)row * N + col] = bv;
        }
      }
    }
  }
}

// ---------------- q/k rmsnorm + rope + relu -> qf/kf (bf16 BHLD) ----------------
// R3: one block per (row, which) — no q/k serialization within a block.
__global__ __launch_bounds__(256) void k_qknorm(
    const unsigned short* __restrict__ qb, const unsigned short* __restrict__ kb,
    const float* __restrict__ gq, const float* __restrict__ gk,
    const float* __restrict__ cosT, const float* __restrict__ sinT,
    unsigned short* __restrict__ qfb, unsigned short* __restrict__ kfb) {
  const int row = blockIdx.x >> 1;
  const int which = blockIdx.x & 1;
  const int l = row & 4095;
  const int b = row >> 12;
  const int t = threadIdx.x;
  __shared__ float red[4];
  __shared__ float s_sc;
  const int d = t * 4;
  const int h = d >> 6;
  const int i0 = (d & 63) >> 1;
  const float c0 = cosT[l * 32 + i0], s0 = sinT[l * 32 + i0];
  const float c1 = cosT[l * 32 + i0 + 1], s1 = sinT[l * 32 + i0 + 1];
  const unsigned short* src = which ? kb : qb;
  const float* g = which ? gk : gq;
  unsigned short* dst = which ? kfb : qfb;
  ushort4 u = *reinterpret_cast<const ushort4*>(src + (size_t)row * 1024 + d);
  float v0 = bf2f(u.x), v1 = bf2f(u.y), v2 = bf2f(u.z), v3 = bf2f(u.w);
  float ss = v0 * v0 + v1 * v1 + v2 * v2 + v3 * v3;
#pragma unroll
  for (int off = 32; off; off >>= 1) ss += __shfl_down(ss, off, 64);
  if ((t & 63) == 0) red[t >> 6] = ss;
  __syncthreads();
  if (t == 0)
    s_sc = rsqrtf((red[0] + red[1] + red[2] + red[3]) * (1.0f / 1024.0f) + RMS_EPS);
  __syncthreads();
  const float sc = s_sc;
  float x0 = v0 * sc * g[d], x1 = v1 * sc * g[d + 1];
  float x2 = v2 * sc * g[d + 2], x3 = v3 * sc * g[d + 3];
  float r0 = x0 * c0 - x1 * s0, r1 = x0 * s0 + x1 * c0;
  float r2 = x2 * c1 - x3 * s1, r3 = x2 * s1 + x3 * c1;
  ushort4 o = { f2bf(fmaxf(r0, 0.f)), f2bf(fmaxf(r1, 0.f)),
                f2bf(fmaxf(r2, 0.f)), f2bf(fmaxf(r3, 0.f)) };
  *reinterpret_cast<ushort4*>(dst + (((size_t)(b * 16 + h)) * 4096 + l) * 64 + (d & 63)) = o;
}

// ---------------- vk[p][d] = sum_l vpad[l][p]*kf[l][d] (per bh) ----------------
__global__ __launch_bounds__(256) void k_vk(const unsigned short* __restrict__ vb,
                                            const unsigned short* __restrict__ kfb,
                                            float* __restrict__ vk) {
  const int bh = blockIdx.x >> 4;
  const int chunk = blockIdx.x & 15;
  const int t = threadIdx.x;
  const int wv = t >> 6, tx = t & 63;
  __shared__ float vt[64 * 64];
  __shared__ float kt[64 * 64];
  float acc[16] = {};
  float accD = 0.f;
  const int lb = chunk * 256;
  for (int tile = 0; tile < 4; ++tile) {
    const size_t rowbase = ((size_t)bh * 4096 + lb + tile * 64) * 64;
#pragma unroll
    for (int r = 0; r < 4; ++r) {
      int e = r * 1024 + t * 4;
      ushort4 uv = *reinterpret_cast<const ushort4*>(vb + rowbase + e);
      ushort4 uk = *reinterpret_cast<const ushort4*>(kfb + rowbase + e);
      float4 fv = { bf2f(uv.x), bf2f(uv.y), bf2f(uv.z), bf2f(uv.w) };
      float4 fk = { bf2f(uk.x), bf2f(uk.y), bf2f(uk.z), bf2f(uk.w) };
      *reinterpret_cast<float4*>(vt + e) = fv;
      *reinterpret_cast<float4*>(kt + e) = fk;
    }
    __syncthreads();
#pragma unroll 4
    for (int lp = 0; lp < 64; ++lp) {
      float kvv = kt[lp * 64 + tx];
      const float4* vr = reinterpret_cast<const float4*>(vt + lp * 64 + wv * 16);
      float4 v0 = vr[0], v1 = vr[1], v2 = vr[2], v3 = vr[3];
      acc[0] += v0.x * kvv;  acc[1] += v0.y * kvv;
      acc[2] += v0.z * kvv;  acc[3] += v0.w * kvv;
      acc[4] += v1.x * kvv;  acc[5] += v1.y * kvv;
      acc[6] += v1.z * kvv;  acc[7] += v1.w * kvv;
      acc[8] += v2.x * kvv;  acc[9] += v2.y * kvv;
      acc[10] += v2.z * kvv; acc[11] += v2.w * kvv;
      acc[12] += v3.x * kvv; acc[13] += v3.y * kvv;
      acc[14] += v3.z * kvv; acc[15] += v3.w * kvv;
      accD += kvv;
    }
    __syncthreads();
  }
  float* dst = vk + (size_t)bh * 65 * 64;
#pragma unroll
  for (int pp = 0; pp < 16; ++pp) atomicAdd(dst + (wv * 16 + pp) * 64 + tx, acc[pp]);
  if (wv == 0) atomicAdd(dst + 64 * 64 + tx, accD);
}

// ---------------- res = qf . vk^T ; attn = res/(den+eps) -> bf16 BLD ----------------
// R3: MFMA. Per block: bh x 128 L-rows. A = qf tile (128x64 bf16, contiguous ->
// global_load_lds), B = vk (64x64, fp32->bf16 staged once). K=64 -> 2 MFMA steps.
// Denominator via VALU from fp32 vkD row, combined with shfl_xor.
__global__ __launch_bounds__(256) void k_res(const unsigned short* __restrict__ qfb,
                                             const float* __restrict__ vk,
                                             unsigned short* __restrict__ attnb) {
  const int bh = blockIdx.x >> 5;
  const int lt = (blockIdx.x & 31) << 7;
  const int b = bh >> 4, h = bh & 15;
  const int t = threadIdx.x;
  const int wave = t >> 6, lane = t & 63;
  __shared__ unsigned short Aq[128 * 64];   // 16 KB, row-major [l][d]
  __shared__ unsigned short Bv[64 * 64];    // 8 KB, row-major [p][d]
  __shared__ float vkD[64];
  __shared__ float invden[128];

  // stage A: contiguous 16KB; wave stages its own 32 rows (4 x 1KB issues)
  const unsigned short* Ag = qfb + ((size_t)bh * 4096 + lt) * 64;
#pragma unroll
  for (int s = 0; s < 4; ++s)
    stage16(Ag + wave * 2048 + s * 512 + lane * 8, Aq + wave * 2048 + s * 512, lane);

  // stage B: vk fp32 -> bf16 (once; 16 elems/thread)
  const float* vsrc = vk + (size_t)bh * 65 * 64;
  {
    int base = t * 16;
#pragma unroll
    for (int c = 0; c < 4; ++c) {
      float4 f = *reinterpret_cast<const float4*>(vsrc + base + c * 4);
      ushort4 o = { f2bf(f.x), f2bf(f.y), f2bf(f.z), f2bf(f.w) };
      *reinterpret_cast<ushort4*>(Bv + base + c * 4) = o;
    }
  }
  if (t < 64) vkD[t] = vsrc[64 * 64 + t];
  __syncthreads();

  f32x4 acc[2][4] = {};
  const int quad = lane >> 4, m16 = lane & 15;
#pragma unroll
  for (int step = 0; step < 2; ++step) {
    bf16x8 fa[2], fb[4];
#pragma unroll
    for (int i = 0; i < 2; ++i)
      fa[i] = *reinterpret_cast<const bf16x8*>(Aq + (wave * 32 + i * 16 + m16) * 64 +
                                               step * 32 + quad * 8);
#pragma unroll
    for (int j = 0; j < 4; ++j)
      fb[j] = *reinterpret_cast<const bf16x8*>(Bv + (j * 16 + m16) * 64 +
                                               step * 32 + quad * 8);
#pragma unroll
    for (int i = 0; i < 2; ++i)
#pragma unroll
      for (int j = 0; j < 4; ++j)
        acc[i][j] = __builtin_amdgcn_mfma_f32_16x16x32_bf16(fa[i], fb[j], acc[i][j], 0, 0, 0);
  }

  // denominator: 2 threads per row, halves combined via shfl_xor (same wave)
  {
    const unsigned short* qr = Aq + (t >> 1) * 64 + (t & 1) * 32;
    const float* vd = vkD + (t & 1) * 32;
    float ds = 0.f;
#pragma unroll
    for (int c = 0; c < 4; ++c) {
      bf16x8 qv = *reinterpret_cast<const bf16x8*>(qr + c * 8);
#pragma unroll
      for (int j = 0; j < 8; ++j)
        ds += bf2f((unsigned short)qv[j]) * vd[c * 8 + j];
    }
    ds += __shfl_xor(ds, 1, 64);
    if ((t & 1) == 0) invden[t >> 1] = 1.0f / (ds + EPS_LIN);
  }
  // invden rows for this wave are produced by this wave; no block barrier needed,
  // but LDS write->read ordering within wave is handled by compiler waitcnt.
  __syncthreads();

#pragma unroll
  for (int i = 0; i < 2; ++i) {
#pragma unroll
    for (int r = 0; r < 4; ++r) {
      int row = wave * 32 + i * 16 + quad * 4 + r;
      float inv = invden[row];
      unsigned short* dst = attnb + ((size_t)(b * 4096 + lt + row)) * 1024 + h * 64;
#pragma unroll
      for (int j = 0; j < 4; ++j)
        dst[j * 16 + m16] = f2bf(acc[i][j][r] * inv);
    }
  }
}

// ---------------- final rmsnorm (bf16 pre) ----------------
__global__ __launch_bounds__(256) void k_outnorm(const unsigned short* __restrict__ preb,
                                                 const float* __restrict__ gout,
                                                 float* __restrict__ out) {
  const int row = blockIdx.x;
  const int t = threadIdx.x;
  __shared__ float red[4];
  __shared__ float s_sc;
  ushort4 u = *reinterpret_cast<const ushort4*>(preb + (size_t)row * 1024 + t * 4);
  float v0 = bf2f(u.x), v1 = bf2f(u.y), v2 = bf2f(u.z), v3 = bf2f(u.w);
  float ss = v0 * v0 + v1 * v1 + v2 * v2 + v3 * v3;
#pragma unroll
  for (int off = 32; off; off >>= 1) ss += __shfl_down(ss, off, 64);
  if ((t & 63) == 0) red[t >> 6] = ss;
  __syncthreads();
  if (t == 0) s_sc = rsqrtf((red[0] + red[1] + red[2] + red[3]) * (1.0f / 1024.0f) + RMS_EPS);
  __syncthreads();
  const float sc = s_sc;
  const int d = t * 4;
  float4 o = { v0 * sc * gout[d], v1 * sc * gout[d + 1],
               v2 * sc * gout[d + 2], v3 * sc * gout[d + 3] };
  *reinterpret_cast<float4*>(out + (size_t)row * 1024 + d) = o;
}

// ---------------- workspace layout (bytes) ----------------
#define OFF_XB     0ull
#define OFF_WQKVB  33554432ull
#define OFF_WOUTB  39845888ull
#define OFF_QB     41943040ull
#define OFF_KB     75497472ull
#define OFF_VB     109051904ull
#define OFF_QFB    142606336ull
#define OFF_KFB    176160768ull
#define OFF_VK     209715200ull
#define OFF_ATTNB  210780160ull
#define OFF_COST   244334592ull
#define OFF_SINT   244858880ull
#define WS_NEEDED  245383168ull
// preb (bf16, 32MB) aliases OFF_QB (qb dead by then)

extern "C" void kernel_launch(void* const* d_in, const int* in_sizes, int n_in,
                              void* d_out, int out_size, void* d_ws, size_t ws_size,
                              hipStream_t stream) {
  const float* x    = (const float*)d_in[0];
  const float* Wqkv = (const float*)d_in[1];
  const float* bqkv = (const float*)d_in[2];
  const float* gq   = (const float*)d_in[3];
  const float* gk   = (const float*)d_in[4];
  const float* Wout = (const float*)d_in[5];
  const float* bout = (const float*)d_in[6];
  const float* gout = (const float*)d_in[7];

  if (ws_size < WS_NEEDED) return;

  char* ws = (char*)d_ws;
  unsigned short* xb    = (unsigned short*)(ws + OFF_XB);
  unsigned short* wqkvb = (unsigned short*)(ws + OFF_WQKVB);
  unsigned short* woutb = (unsigned short*)(ws + OFF_WOUTB);
  unsigned short* qb    = (unsigned short*)(ws + OFF_QB);
  unsigned short* kb    = (unsigned short*)(ws + OFF_KB);
  unsigned short* vb    = (unsigned short*)(ws + OFF_VB);
  unsigned short* qfb   = (unsigned short*)(ws + OFF_QFB);
  unsigned short* kfb   = (unsigned short*)(ws + OFF_KFB);
  float*          vkbuf = (float*)(ws + OFF_VK);
  unsigned short* attnb = (unsigned short*)(ws + OFF_ATTNB);
  float*          cosT  = (float*)(ws + OFF_COST);
  float*          sinT  = (float*)(ws + OFF_SINT);
  unsigned short* preb  = (unsigned short*)(ws + OFF_QB);  // alias

  k_f32_to_bf16<<<16384, 256, 0, stream>>>(x, xb, 16777216);
  k_f32_to_bf16<<<3072, 256, 0, stream>>>(Wqkv, wqkvb, 3145728);
  k_f32_to_bf16<<<1024, 256, 0, stream>>>(Wout, woutb, 1048576);
  k_rope_table<<<512, 256, 0, stream>>>(cosT, sinT);

  // QKV gemm: M=16384 N=3072 K=1024
  k_gemm_bt<<<128 * 24, 256, 0, stream>>>(xb, wqkvb, bqkv, 16384, 3072, 1024, 0,
                                          qb, kb, vb, nullptr);
  k_qknorm<<<32768, 256, 0, stream>>>(qb, kb, gq, gk, cosT, sinT, qfb, kfb);

  hipMemsetAsync(vkbuf, 0, 64 * 65 * 64 * sizeof(float), stream);
  k_vk<<<1024, 256, 0, stream>>>(vb, kfb, vkbuf);
  k_res<<<2048, 256, 0, stream>>>(qfb, vkbuf, attnb);

  // out gemm: M=16384 N=1024 K=1024 -> preb (bf16, aliases qb region)
  k_gemm_bt<<<128 * 8, 256, 0, stream>>>(attnb, woutb, bout, 16384, 1024, 1024, 1,
                                         nullptr, nullptr, nullptr, preb);
  k_outnorm<<<16384, 256, 0, stream>>>(preb, gout, (float*)d_out);
}

// Round 4
// 407.866 us; speedup vs baseline: 4.2420x; 1.1276x over previous
//
#include <hip/hip_runtime.h>
#include <stdint.h>

#define RMS_EPS 1.1920929e-07f
#define EPS_LIN 1e-6f

typedef __attribute__((ext_vector_type(8))) short bf16x8;
typedef __attribute__((ext_vector_type(4))) float f32x4;

__device__ __forceinline__ unsigned short f2bf(float f) {
  union { float f; unsigned int u; } v; v.f = f;
  unsigned int r = v.u + 0x7fffu + ((v.u >> 16) & 1u);
  return (unsigned short)(r >> 16);
}
__device__ __forceinline__ float bf2f(unsigned short s) {
  union { unsigned int u; float f; } v; v.u = ((unsigned int)s) << 16;
  return v.f;
}

// ---------------- fp32 -> bf16 convert ----------------
__global__ __launch_bounds__(256) void k_f32_to_bf16(const float* __restrict__ src,
                                                     unsigned short* __restrict__ dst, int n) {
  int i = (blockIdx.x * 256 + threadIdx.x) * 4;
  if (i >= n) return;
  float4 v = *reinterpret_cast<const float4*>(src + i);
  ushort4 o = { f2bf(v.x), f2bf(v.y), f2bf(v.z), f2bf(v.w) };
  *reinterpret_cast<ushort4*>(dst + i) = o;
}

// ---------------- rope table: cos/sin (4096 x 32) ----------------
__global__ __launch_bounds__(256) void k_rope_table(float* __restrict__ cosT,
                                                    float* __restrict__ sinT) {
  int idx = blockIdx.x * 256 + threadIdx.x;
  if (idx >= 4096 * 32) return;
  int l = idx >> 5, i = idx & 31;
  float inv_freq = expf(-((float)(2 * i) / 64.0f) * logf(10000.0f));
  float ang = (float)l * inv_freq;
  cosT[idx] = cosf(ang);
  sinT[idx] = sinf(ang);
}

// ---------------- async global->LDS 16B stage ----------------
__device__ __forceinline__ void stage16(const unsigned short* g, unsigned short* lds_base,
                                        int lane) {
#if __has_builtin(__builtin_amdgcn_global_load_lds)
  __builtin_amdgcn_global_load_lds(
      (const __attribute__((address_space(1))) unsigned int*)g,
      (__attribute__((address_space(3))) unsigned int*)lds_base, 16, 0, 0);
#else
  *reinterpret_cast<uint4*>(lds_base + lane * 8) = *reinterpret_cast<const uint4*>(g);
#endif
}

// ---------------- bf16 GEMM C = A(MxK) * B(NxK)^T + bias ----------------
// R4: BK=64 (halves barrier drains), XOR-swizzled LDS (unit (row,ku) stored at
// row*8 + (ku^(row&7)) 16B-units) -> conflict-free ds_read_b128 at 128B row
// stride. Swizzle is applied on the GLOBAL side of global_load_lds (per-lane
// address permute within each row's 128B segment), LDS side stays contiguous.
// mode 0: QKV gemm -> scatter q, k (bf16 row-major), v (bf16 BHLD)
// mode 1: out gemm -> preb (bf16 row-major)
__global__ __launch_bounds__(256, 3) void k_gemm_bt(
    const unsigned short* __restrict__ A, const unsigned short* __restrict__ Bw,
    const float* __restrict__ bias, int M, int N, int K, int mode,
    unsigned short* __restrict__ qb, unsigned short* __restrict__ kb,
    unsigned short* __restrict__ vb, unsigned short* __restrict__ preb) {
  __shared__ unsigned short As[128 * 64];   // 16 KB, swizzled
  __shared__ unsigned short Bs[128 * 64];   // 16 KB, swizzled
  const int nt = N >> 7;
  const int bm = blockIdx.x / nt, bn = blockIdx.x % nt;
  const int m0 = bm << 7, n0 = bn << 7;
  const int t = threadIdx.x;
  const int wave = t >> 6, lane = t & 63;
  const int wr = wave >> 1, wc = wave & 1;
  const int quad = lane >> 4, m16 = lane & 15;

  // staging decode: unit u = wave*256 + s*64 + lane; row=u>>3; ku=(u&7)^(row&7)
  const unsigned short* ApS[4];
  const unsigned short* BpS[4];
  unsigned short* AlS[4];
  unsigned short* BlS[4];
#pragma unroll
  for (int s = 0; s < 4; ++s) {
    int u = wave * 256 + s * 64 + lane;
    int row = u >> 3;
    int ku = (u & 7) ^ (row & 7);
    ApS[s] = A + (size_t)(m0 + row) * K + ku * 8;
    BpS[s] = Bw + (size_t)(n0 + row) * K + ku * 8;
    AlS[s] = As + (size_t)(wave * 256 + s * 64) * 8;  // wave-uniform
    BlS[s] = Bs + (size_t)(wave * 256 + s * 64) * 8;
  }

  // fragment read offsets (in shorts): row_f*64 swizzled
  int offA[4][2], offB[4][2];
#pragma unroll
  for (int i = 0; i < 4; ++i) {
    int rowA = wr * 64 + i * 16 + m16;
    int rowB = wc * 64 + i * 16 + m16;
#pragma unroll
    for (int ks = 0; ks < 2; ++ks) {
      int kuf = ks * 4 + quad;
      offA[i][ks] = (rowA * 8 + (kuf ^ (rowA & 7))) * 8;
      offB[i][ks] = (rowB * 8 + (kuf ^ (rowB & 7))) * 8;
    }
  }

  f32x4 acc[4][4] = {};

  for (int k0 = 0; k0 < K; k0 += 64) {
#pragma unroll
    for (int s = 0; s < 4; ++s) {
      stage16(ApS[s] + k0, AlS[s], lane);
      stage16(BpS[s] + k0, BlS[s], lane);
    }
    __syncthreads();
#pragma unroll
    for (int ks = 0; ks < 2; ++ks) {
      bf16x8 fa[4], fb[4];
#pragma unroll
      for (int i = 0; i < 4; ++i)
        fa[i] = *reinterpret_cast<const bf16x8*>(As + offA[i][ks]);
#pragma unroll
      for (int j = 0; j < 4; ++j)
        fb[j] = *reinterpret_cast<const bf16x8*>(Bs + offB[j][ks]);
#pragma unroll
      for (int i = 0; i < 4; ++i)
#pragma unroll
        for (int j = 0; j < 4; ++j)
          acc[i][j] = __builtin_amdgcn_mfma_f32_16x16x32_bf16(fa[i], fb[j], acc[i][j], 0, 0, 0);
    }
    __syncthreads();
  }

#pragma unroll
  for (int i = 0; i < 4; ++i) {
    int rbase = m0 + wr * 64 + i * 16 + quad * 4;
#pragma unroll
    for (int j = 0; j < 4; ++j) {
      int col = n0 + wc * 64 + j * 16 + m16;
      float bc = bias[col];
#pragma unroll
      for (int r = 0; r < 4; ++r) {
        int row = rbase + r;
        float val = acc[i][j][r] + bc;
        unsigned short bv = f2bf(val);
        if (mode == 0) {
          if (col < 1024) {
            qb[(size_t)row * 1024 + col] = bv;
          } else if (col < 2048) {
            kb[(size_t)row * 1024 + (col - 1024)] = bv;
          } else {
            int h = (col - 2048) >> 6, d = col & 63;
            int b = row >> 12, l = row & 4095;
            vb[(((size_t)(b * 16 + h)) * 4096 + l) * 64 + d] = bv;
          }
        } else {
          preb[(size_t)row * N + col] = bv;
        }
      }
    }
  }
}

// ---------------- q/k rmsnorm + rope + relu -> qf/kf (bf16 BHLD) ----------------
__global__ __launch_bounds__(256) void k_qknorm(
    const unsigned short* __restrict__ qb, const unsigned short* __restrict__ kb,
    const float* __restrict__ gq, const float* __restrict__ gk,
    const float* __restrict__ cosT, const float* __restrict__ sinT,
    unsigned short* __restrict__ qfb, unsigned short* __restrict__ kfb) {
  const int row = blockIdx.x >> 1;
  const int which = blockIdx.x & 1;
  const int l = row & 4095;
  const int b = row >> 12;
  const int t = threadIdx.x;
  __shared__ float red[4];
  __shared__ float s_sc;
  const int d = t * 4;
  const int h = d >> 6;
  const int i0 = (d & 63) >> 1;
  const float c0 = cosT[l * 32 + i0], s0 = sinT[l * 32 + i0];
  const float c1 = cosT[l * 32 + i0 + 1], s1 = sinT[l * 32 + i0 + 1];
  const unsigned short* src = which ? kb : qb;
  const float* g = which ? gk : gq;
  unsigned short* dst = which ? kfb : qfb;
  ushort4 u = *reinterpret_cast<const ushort4*>(src + (size_t)row * 1024 + d);
  float v0 = bf2f(u.x), v1 = bf2f(u.y), v2 = bf2f(u.z), v3 = bf2f(u.w);
  float ss = v0 * v0 + v1 * v1 + v2 * v2 + v3 * v3;
#pragma unroll
  for (int off = 32; off; off >>= 1) ss += __shfl_down(ss, off, 64);
  if ((t & 63) == 0) red[t >> 6] = ss;
  __syncthreads();
  if (t == 0)
    s_sc = rsqrtf((red[0] + red[1] + red[2] + red[3]) * (1.0f / 1024.0f) + RMS_EPS);
  __syncthreads();
  const float sc = s_sc;
  float x0 = v0 * sc * g[d], x1 = v1 * sc * g[d + 1];
  float x2 = v2 * sc * g[d + 2], x3 = v3 * sc * g[d + 3];
  float r0 = x0 * c0 - x1 * s0, r1 = x0 * s0 + x1 * c0;
  float r2 = x2 * c1 - x3 * s1, r3 = x2 * s1 + x3 * c1;
  ushort4 o = { f2bf(fmaxf(r0, 0.f)), f2bf(fmaxf(r1, 0.f)),
                f2bf(fmaxf(r2, 0.f)), f2bf(fmaxf(r3, 0.f)) };
  *reinterpret_cast<ushort4*>(dst + (((size_t)(b * 16 + h)) * 4096 + l) * 64 + (d & 63)) = o;
}

// ---------------- vk[p][d] = sum_l vpad[l][p]*kf[l][d] (per bh) ----------------
__global__ __launch_bounds__(256) void k_vk(const unsigned short* __restrict__ vb,
                                            const unsigned short* __restrict__ kfb,
                                            float* __restrict__ vk) {
  const int bh = blockIdx.x >> 4;
  const int chunk = blockIdx.x & 15;
  const int t = threadIdx.x;
  const int wv = t >> 6, tx = t & 63;
  __shared__ float vt[64 * 64];
  __shared__ float kt[64 * 64];
  float acc[16] = {};
  float accD = 0.f;
  const int lb = chunk * 256;
  for (int tile = 0; tile < 4; ++tile) {
    const size_t rowbase = ((size_t)bh * 4096 + lb + tile * 64) * 64;
#pragma unroll
    for (int r = 0; r < 4; ++r) {
      int e = r * 1024 + t * 4;
      ushort4 uv = *reinterpret_cast<const ushort4*>(vb + rowbase + e);
      ushort4 uk = *reinterpret_cast<const ushort4*>(kfb + rowbase + e);
      float4 fv = { bf2f(uv.x), bf2f(uv.y), bf2f(uv.z), bf2f(uv.w) };
      float4 fk = { bf2f(uk.x), bf2f(uk.y), bf2f(uk.z), bf2f(uk.w) };
      *reinterpret_cast<float4*>(vt + e) = fv;
      *reinterpret_cast<float4*>(kt + e) = fk;
    }
    __syncthreads();
#pragma unroll 4
    for (int lp = 0; lp < 64; ++lp) {
      float kvv = kt[lp * 64 + tx];
      const float4* vr = reinterpret_cast<const float4*>(vt + lp * 64 + wv * 16);
      float4 v0 = vr[0], v1 = vr[1], v2 = vr[2], v3 = vr[3];
      acc[0] += v0.x * kvv;  acc[1] += v0.y * kvv;
      acc[2] += v0.z * kvv;  acc[3] += v0.w * kvv;
      acc[4] += v1.x * kvv;  acc[5] += v1.y * kvv;
      acc[6] += v1.z * kvv;  acc[7] += v1.w * kvv;
      acc[8] += v2.x * kvv;  acc[9] += v2.y * kvv;
      acc[10] += v2.z * kvv; acc[11] += v2.w * kvv;
      acc[12] += v3.x * kvv; acc[13] += v3.y * kvv;
      acc[14] += v3.z * kvv; acc[15] += v3.w * kvv;
      accD += kvv;
    }
    __syncthreads();
  }
  float* dst = vk + (size_t)bh * 65 * 64;
#pragma unroll
  for (int pp = 0; pp < 16; ++pp) atomicAdd(dst + (wv * 16 + pp) * 64 + tx, acc[pp]);
  if (wv == 0) atomicAdd(dst + 64 * 64 + tx, accD);
}

// ---------------- res = qf . vk^T ; attn = res/(den+eps) -> bf16 BLD ----------------
__global__ __launch_bounds__(256) void k_res(const unsigned short* __restrict__ qfb,
                                             const float* __restrict__ vk,
                                             unsigned short* __restrict__ attnb) {
  const int bh = blockIdx.x >> 5;
  const int lt = (blockIdx.x & 31) << 7;
  const int b = bh >> 4, h = bh & 15;
  const int t = threadIdx.x;
  const int wave = t >> 6, lane = t & 63;
  __shared__ unsigned short Aq[128 * 64];   // 16 KB, row-major [l][d]
  __shared__ unsigned short Bv[64 * 64];    // 8 KB, row-major [p][d]
  __shared__ float vkD[64];
  __shared__ float invden[128];

  const unsigned short* Ag = qfb + ((size_t)bh * 4096 + lt) * 64;
#pragma unroll
  for (int s = 0; s < 4; ++s)
    stage16(Ag + wave * 2048 + s * 512 + lane * 8, Aq + wave * 2048 + s * 512, lane);

  const float* vsrc = vk + (size_t)bh * 65 * 64;
  {
    int base = t * 16;
#pragma unroll
    for (int c = 0; c < 4; ++c) {
      float4 f = *reinterpret_cast<const float4*>(vsrc + base + c * 4);
      ushort4 o = { f2bf(f.x), f2bf(f.y), f2bf(f.z), f2bf(f.w) };
      *reinterpret_cast<ushort4*>(Bv + base + c * 4) = o;
    }
  }
  if (t < 64) vkD[t] = vsrc[64 * 64 + t];
  __syncthreads();

  f32x4 acc[2][4] = {};
  const int quad = lane >> 4, m16 = lane & 15;
#pragma unroll
  for (int step = 0; step < 2; ++step) {
    bf16x8 fa[2], fb[4];
#pragma unroll
    for (int i = 0; i < 2; ++i)
      fa[i] = *reinterpret_cast<const bf16x8*>(Aq + (wave * 32 + i * 16 + m16) * 64 +
                                               step * 32 + quad * 8);
#pragma unroll
    for (int j = 0; j < 4; ++j)
      fb[j] = *reinterpret_cast<const bf16x8*>(Bv + (j * 16 + m16) * 64 +
                                               step * 32 + quad * 8);
#pragma unroll
    for (int i = 0; i < 2; ++i)
#pragma unroll
      for (int j = 0; j < 4; ++j)
        acc[i][j] = __builtin_amdgcn_mfma_f32_16x16x32_bf16(fa[i], fb[j], acc[i][j], 0, 0, 0);
  }

  {
    const unsigned short* qr = Aq + (t >> 1) * 64 + (t & 1) * 32;
    const float* vd = vkD + (t & 1) * 32;
    float ds = 0.f;
#pragma unroll
    for (int c = 0; c < 4; ++c) {
      bf16x8 qv = *reinterpret_cast<const bf16x8*>(qr + c * 8);
#pragma unroll
      for (int j = 0; j < 8; ++j)
        ds += bf2f((unsigned short)qv[j]) * vd[c * 8 + j];
    }
    ds += __shfl_xor(ds, 1, 64);
    if ((t & 1) == 0) invden[t >> 1] = 1.0f / (ds + EPS_LIN);
  }
  __syncthreads();

#pragma unroll
  for (int i = 0; i < 2; ++i) {
#pragma unroll
    for (int r = 0; r < 4; ++r) {
      int row = wave * 32 + i * 16 + quad * 4 + r;
      float inv = invden[row];
      unsigned short* dst = attnb + ((size_t)(b * 4096 + lt + row)) * 1024 + h * 64;
#pragma unroll
      for (int j = 0; j < 4; ++j)
        dst[j * 16 + m16] = f2bf(acc[i][j][r] * inv);
    }
  }
}

// ---------------- final rmsnorm (bf16 pre) ----------------
__global__ __launch_bounds__(256) void k_outnorm(const unsigned short* __restrict__ preb,
                                                 const float* __restrict__ gout,
                                                 float* __restrict__ out) {
  const int row = blockIdx.x;
  const int t = threadIdx.x;
  __shared__ float red[4];
  __shared__ float s_sc;
  ushort4 u = *reinterpret_cast<const ushort4*>(preb + (size_t)row * 1024 + t * 4);
  float v0 = bf2f(u.x), v1 = bf2f(u.y), v2 = bf2f(u.z), v3 = bf2f(u.w);
  float ss = v0 * v0 + v1 * v1 + v2 * v2 + v3 * v3;
#pragma unroll
  for (int off = 32; off; off >>= 1) ss += __shfl_down(ss, off, 64);
  if ((t & 63) == 0) red[t >> 6] = ss;
  __syncthreads();
  if (t == 0) s_sc = rsqrtf((red[0] + red[1] + red[2] + red[3]) * (1.0f / 1024.0f) + RMS_EPS);
  __syncthreads();
  const float sc = s_sc;
  const int d = t * 4;
  float4 o = { v0 * sc * gout[d], v1 * sc * gout[d + 1],
               v2 * sc * gout[d + 2], v3 * sc * gout[d + 3] };
  *reinterpret_cast<float4*>(out + (size_t)row * 1024 + d) = o;
}

// ---------------- workspace layout (bytes) ----------------
#define OFF_XB     0ull
#define OFF_WQKVB  33554432ull
#define OFF_WOUTB  39845888ull
#define OFF_QB     41943040ull
#define OFF_KB     75497472ull
#define OFF_VB     109051904ull
#define OFF_QFB    142606336ull
#define OFF_KFB    176160768ull
#define OFF_VK     209715200ull
#define OFF_ATTNB  210780160ull
#define OFF_COST   244334592ull
#define OFF_SINT   244858880ull
#define WS_NEEDED  245383168ull
// preb (bf16, 32MB) aliases OFF_QB (qb dead by then)

extern "C" void kernel_launch(void* const* d_in, const int* in_sizes, int n_in,
                              void* d_out, int out_size, void* d_ws, size_t ws_size,
                              hipStream_t stream) {
  const float* x    = (const float*)d_in[0];
  const float* Wqkv = (const float*)d_in[1];
  const float* bqkv = (const float*)d_in[2];
  const float* gq   = (const float*)d_in[3];
  const float* gk   = (const float*)d_in[4];
  const float* Wout = (const float*)d_in[5];
  const float* bout = (const float*)d_in[6];
  const float* gout = (const float*)d_in[7];

  if (ws_size < WS_NEEDED) return;

  char* ws = (char*)d_ws;
  unsigned short* xb    = (unsigned short*)(ws + OFF_XB);
  unsigned short* wqkvb = (unsigned short*)(ws + OFF_WQKVB);
  unsigned short* woutb = (unsigned short*)(ws + OFF_WOUTB);
  unsigned short* qb    = (unsigned short*)(ws + OFF_QB);
  unsigned short* kb    = (unsigned short*)(ws + OFF_KB);
  unsigned short* vb    = (unsigned short*)(ws + OFF_VB);
  unsigned short* qfb   = (unsigned short*)(ws + OFF_QFB);
  unsigned short* kfb   = (unsigned short*)(ws + OFF_KFB);
  float*          vkbuf = (float*)(ws + OFF_VK);
  unsigned short* attnb = (unsigned short*)(ws + OFF_ATTNB);
  float*          cosT  = (float*)(ws + OFF_COST);
  float*          sinT  = (float*)(ws + OFF_SINT);
  unsigned short* preb  = (unsigned short*)(ws + OFF_QB);  // alias

  k_f32_to_bf16<<<16384, 256, 0, stream>>>(x, xb, 16777216);
  k_f32_to_bf16<<<3072, 256, 0, stream>>>(Wqkv, wqkvb, 3145728);
  k_f32_to_bf16<<<1024, 256, 0, stream>>>(Wout, woutb, 1048576);
  k_rope_table<<<512, 256, 0, stream>>>(cosT, sinT);

  // QKV gemm: M=16384 N=3072 K=1024
  k_gemm_bt<<<128 * 24, 256, 0, stream>>>(xb, wqkvb, bqkv, 16384, 3072, 1024, 0,
                                          qb, kb, vb, nullptr);
  k_qknorm<<<32768, 256, 0, stream>>>(qb, kb, gq, gk, cosT, sinT, qfb, kfb);

  hipMemsetAsync(vkbuf, 0, 64 * 65 * 64 * sizeof(float), stream);
  k_vk<<<1024, 256, 0, stream>>>(vb, kfb, vkbuf);
  k_res<<<2048, 256, 0, stream>>>(qfb, vkbuf, attnb);

  // out gemm: M=16384 N=1024 K=1024 -> preb (bf16, aliases qb region)
  k_gemm_bt<<<128 * 8, 256, 0, stream>>>(attnb, woutb, bout, 16384, 1024, 1024, 1,
                                         nullptr, nullptr, nullptr, preb);
  k_outnorm<<<16384, 256, 0, stream>>>(preb, gout, (float*)d_out);
}

// Round 5
// 395.939 us; speedup vs baseline: 4.3698x; 1.0301x over previous
//
#include <hip/hip_runtime.h>
#include <stdint.h>

#define RMS_EPS 1.1920929e-07f
#define EPS_LIN 1e-6f

typedef __attribute__((ext_vector_type(8))) short bf16x8;
typedef __attribute__((ext_vector_type(4))) float f32x4;

__device__ __forceinline__ unsigned short f2bf(float f) {
  union { float f; unsigned int u; } v; v.f = f;
  unsigned int r = v.u + 0x7fffu + ((v.u >> 16) & 1u);
  return (unsigned short)(r >> 16);
}
__device__ __forceinline__ float bf2f(unsigned short s) {
  union { unsigned int u; float f; } v; v.u = ((unsigned int)s) << 16;
  return v.f;
}

// ---------------- fused init: f32->bf16 x3 + rope table + vkbuf zero ----------------
// block partition: [0,16384) x | [16384,19456) Wqkv | [19456,20480) Wout |
//                  [20480,20992) rope | [20992,21252) zero vkbuf
__global__ __launch_bounds__(256) void k_init(
    const float* __restrict__ x, const float* __restrict__ Wqkv,
    const float* __restrict__ Wout,
    unsigned short* __restrict__ xb, unsigned short* __restrict__ wqkvb,
    unsigned short* __restrict__ woutb,
    float* __restrict__ cosT, float* __restrict__ sinT,
    float* __restrict__ vkbuf) {
  const int blk = blockIdx.x;
  const int t = threadIdx.x;
  if (blk < 20480) {
    const float* src;
    unsigned short* dst;
    int base;
    if (blk < 16384) { src = x; dst = xb; base = blk; }
    else if (blk < 19456) { src = Wqkv; dst = wqkvb; base = blk - 16384; }
    else { src = Wout; dst = woutb; base = blk - 19456; }
    int i = (base * 256 + t) * 4;
    float4 v = *reinterpret_cast<const float4*>(src + i);
    ushort4 o = { f2bf(v.x), f2bf(v.y), f2bf(v.z), f2bf(v.w) };
    *reinterpret_cast<ushort4*>(dst + i) = o;
  } else if (blk < 20992) {
    int idx = (blk - 20480) * 256 + t;
    int l = idx >> 5, i = idx & 31;
    float inv_freq = expf(-((float)(2 * i) / 64.0f) * logf(10000.0f));
    float ang = (float)l * inv_freq;
    cosT[idx] = cosf(ang);
    sinT[idx] = sinf(ang);
  } else {
    int i = ((blk - 20992) * 256 + t) * 4;
    if (i < 64 * 65 * 64) {
      float4 z = { 0.f, 0.f, 0.f, 0.f };
      *reinterpret_cast<float4*>(vkbuf + i) = z;
    }
  }
}

// ---------------- async global->LDS 16B stage ----------------
__device__ __forceinline__ void stage16(const unsigned short* g, unsigned short* lds_base,
                                        int lane) {
#if __has_builtin(__builtin_amdgcn_global_load_lds)
  __builtin_amdgcn_global_load_lds(
      (const __attribute__((address_space(1))) unsigned int*)g,
      (__attribute__((address_space(3))) unsigned int*)lds_base, 16, 0, 0);
#else
  *reinterpret_cast<uint4*>(lds_base + lane * 8) = *reinterpret_cast<const uint4*>(g);
#endif
}

// ---------------- bf16 GEMM C = A(MxK) * B(NxK)^T + bias ----------------
// BK=64, XOR-swizzled LDS (R4: conflicts=0, 918 TF). Unchanged in R5.
__global__ __launch_bounds__(256, 3) void k_gemm_bt(
    const unsigned short* __restrict__ A, const unsigned short* __restrict__ Bw,
    const float* __restrict__ bias, int M, int N, int K, int mode,
    unsigned short* __restrict__ qb, unsigned short* __restrict__ kb,
    unsigned short* __restrict__ vb, unsigned short* __restrict__ preb) {
  __shared__ unsigned short As[128 * 64];
  __shared__ unsigned short Bs[128 * 64];
  const int nt = N >> 7;
  const int bm = blockIdx.x / nt, bn = blockIdx.x % nt;
  const int m0 = bm << 7, n0 = bn << 7;
  const int t = threadIdx.x;
  const int wave = t >> 6, lane = t & 63;
  const int wr = wave >> 1, wc = wave & 1;
  const int quad = lane >> 4, m16 = lane & 15;

  const unsigned short* ApS[4];
  const unsigned short* BpS[4];
  unsigned short* AlS[4];
  unsigned short* BlS[4];
#pragma unroll
  for (int s = 0; s < 4; ++s) {
    int u = wave * 256 + s * 64 + lane;
    int row = u >> 3;
    int ku = (u & 7) ^ (row & 7);
    ApS[s] = A + (size_t)(m0 + row) * K + ku * 8;
    BpS[s] = Bw + (size_t)(n0 + row) * K + ku * 8;
    AlS[s] = As + (size_t)(wave * 256 + s * 64) * 8;
    BlS[s] = Bs + (size_t)(wave * 256 + s * 64) * 8;
  }

  int offA[4][2], offB[4][2];
#pragma unroll
  for (int i = 0; i < 4; ++i) {
    int rowA = wr * 64 + i * 16 + m16;
    int rowB = wc * 64 + i * 16 + m16;
#pragma unroll
    for (int ks = 0; ks < 2; ++ks) {
      int kuf = ks * 4 + quad;
      offA[i][ks] = (rowA * 8 + (kuf ^ (rowA & 7))) * 8;
      offB[i][ks] = (rowB * 8 + (kuf ^ (rowB & 7))) * 8;
    }
  }

  f32x4 acc[4][4] = {};

  for (int k0 = 0; k0 < K; k0 += 64) {
#pragma unroll
    for (int s = 0; s < 4; ++s) {
      stage16(ApS[s] + k0, AlS[s], lane);
      stage16(BpS[s] + k0, BlS[s], lane);
    }
    __syncthreads();
#pragma unroll
    for (int ks = 0; ks < 2; ++ks) {
      bf16x8 fa[4], fb[4];
#pragma unroll
      for (int i = 0; i < 4; ++i)
        fa[i] = *reinterpret_cast<const bf16x8*>(As + offA[i][ks]);
#pragma unroll
      for (int j = 0; j < 4; ++j)
        fb[j] = *reinterpret_cast<const bf16x8*>(Bs + offB[j][ks]);
#pragma unroll
      for (int i = 0; i < 4; ++i)
#pragma unroll
        for (int j = 0; j < 4; ++j)
          acc[i][j] = __builtin_amdgcn_mfma_f32_16x16x32_bf16(fa[i], fb[j], acc[i][j], 0, 0, 0);
    }
    __syncthreads();
  }

#pragma unroll
  for (int i = 0; i < 4; ++i) {
    int rbase = m0 + wr * 64 + i * 16 + quad * 4;
#pragma unroll
    for (int j = 0; j < 4; ++j) {
      int col = n0 + wc * 64 + j * 16 + m16;
      float bc = bias[col];
#pragma unroll
      for (int r = 0; r < 4; ++r) {
        int row = rbase + r;
        float val = acc[i][j][r] + bc;
        unsigned short bv = f2bf(val);
        if (mode == 0) {
          if (col < 1024) {
            qb[(size_t)row * 1024 + col] = bv;
          } else if (col < 2048) {
            kb[(size_t)row * 1024 + (col - 1024)] = bv;
          } else {
            int h = (col - 2048) >> 6, d = col & 63;
            int b = row >> 12, l = row & 4095;
            vb[(((size_t)(b * 16 + h)) * 4096 + l) * 64 + d] = bv;
          }
        } else {
          preb[(size_t)row * N + col] = bv;
        }
      }
    }
  }
}

// ---------------- q/k rmsnorm + rope + relu (R5: wave-per-row, no barriers) ----------
// wave id -> (row, which); lane holds 16 elems (4 x ushort4 at d = c*256 + lane*4).
__global__ __launch_bounds__(256) void k_qknorm(
    const unsigned short* __restrict__ qb, const unsigned short* __restrict__ kb,
    const float* __restrict__ gq, const float* __restrict__ gk,
    const float* __restrict__ cosT, const float* __restrict__ sinT,
    unsigned short* __restrict__ qfb, unsigned short* __restrict__ kfb) {
  const int wid = (blockIdx.x << 2) + (threadIdx.x >> 6);
  const int row = wid >> 1;
  const int which = wid & 1;
  const int lane = threadIdx.x & 63;
  const int l = row & 4095;
  const int b = row >> 12;
  const unsigned short* src = (which ? kb : qb) + (size_t)row * 1024;
  const float* g = which ? gk : gq;
  unsigned short* dstb = which ? kfb : qfb;

  float v[16];
  float ss = 0.f;
#pragma unroll
  for (int c = 0; c < 4; ++c) {
    int d = c * 256 + lane * 4;
    ushort4 u = *reinterpret_cast<const ushort4*>(src + d);
    float a0 = bf2f(u.x), a1 = bf2f(u.y), a2 = bf2f(u.z), a3 = bf2f(u.w);
    v[c * 4 + 0] = a0; v[c * 4 + 1] = a1; v[c * 4 + 2] = a2; v[c * 4 + 3] = a3;
    ss += a0 * a0 + a1 * a1 + a2 * a2 + a3 * a3;
  }
#pragma unroll
  for (int off = 1; off < 64; off <<= 1) ss += __shfl_xor(ss, off, 64);
  const float sc = rsqrtf(ss * (1.0f / 1024.0f) + RMS_EPS);

#pragma unroll
  for (int c = 0; c < 4; ++c) {
    int d = c * 256 + lane * 4;
    int i0 = (d & 63) >> 1;
    float c0 = cosT[l * 32 + i0], s0 = sinT[l * 32 + i0];
    float c1 = cosT[l * 32 + i0 + 1], s1 = sinT[l * 32 + i0 + 1];
    float x0 = v[c * 4 + 0] * sc * g[d];
    float x1 = v[c * 4 + 1] * sc * g[d + 1];
    float x2 = v[c * 4 + 2] * sc * g[d + 2];
    float x3 = v[c * 4 + 3] * sc * g[d + 3];
    float r0 = x0 * c0 - x1 * s0, r1 = x0 * s0 + x1 * c0;
    float r2 = x2 * c1 - x3 * s1, r3 = x2 * s1 + x3 * c1;
    ushort4 o = { f2bf(fmaxf(r0, 0.f)), f2bf(fmaxf(r1, 0.f)),
                  f2bf(fmaxf(r2, 0.f)), f2bf(fmaxf(r3, 0.f)) };
    int h = d >> 6;
    *reinterpret_cast<ushort4*>(dstb + (((size_t)(b * 16 + h)) * 4096 + l) * 64 + (d & 63)) = o;
  }
}

// ---------------- vk[p][d] = sum_l vpad[l][p]*kf[l][d] (per bh) ----------------
__global__ __launch_bounds__(256) void k_vk(const unsigned short* __restrict__ vb,
                                            const unsigned short* __restrict__ kfb,
                                            float* __restrict__ vk) {
  const int bh = blockIdx.x >> 4;
  const int chunk = blockIdx.x & 15;
  const int t = threadIdx.x;
  const int wv = t >> 6, tx = t & 63;
  __shared__ float vt[64 * 64];
  __shared__ float kt[64 * 64];
  float acc[16] = {};
  float accD = 0.f;
  const int lb = chunk * 256;
  for (int tile = 0; tile < 4; ++tile) {
    const size_t rowbase = ((size_t)bh * 4096 + lb + tile * 64) * 64;
#pragma unroll
    for (int r = 0; r < 4; ++r) {
      int e = r * 1024 + t * 4;
      ushort4 uv = *reinterpret_cast<const ushort4*>(vb + rowbase + e);
      ushort4 uk = *reinterpret_cast<const ushort4*>(kfb + rowbase + e);
      float4 fv = { bf2f(uv.x), bf2f(uv.y), bf2f(uv.z), bf2f(uv.w) };
      float4 fk = { bf2f(uk.x), bf2f(uk.y), bf2f(uk.z), bf2f(uk.w) };
      *reinterpret_cast<float4*>(vt + e) = fv;
      *reinterpret_cast<float4*>(kt + e) = fk;
    }
    __syncthreads();
#pragma unroll 4
    for (int lp = 0; lp < 64; ++lp) {
      float kvv = kt[lp * 64 + tx];
      const float4* vr = reinterpret_cast<const float4*>(vt + lp * 64 + wv * 16);
      float4 v0 = vr[0], v1 = vr[1], v2 = vr[2], v3 = vr[3];
      acc[0] += v0.x * kvv;  acc[1] += v0.y * kvv;
      acc[2] += v0.z * kvv;  acc[3] += v0.w * kvv;
      acc[4] += v1.x * kvv;  acc[5] += v1.y * kvv;
      acc[6] += v1.z * kvv;  acc[7] += v1.w * kvv;
      acc[8] += v2.x * kvv;  acc[9] += v2.y * kvv;
      acc[10] += v2.z * kvv; acc[11] += v2.w * kvv;
      acc[12] += v3.x * kvv; acc[13] += v3.y * kvv;
      acc[14] += v3.z * kvv; acc[15] += v3.w * kvv;
      accD += kvv;
    }
    __syncthreads();
  }
  float* dst = vk + (size_t)bh * 65 * 64;
#pragma unroll
  for (int pp = 0; pp < 16; ++pp) atomicAdd(dst + (wv * 16 + pp) * 64 + tx, acc[pp]);
  if (wv == 0) atomicAdd(dst + 64 * 64 + tx, accD);
}

// ---------------- res = qf . vk^T ; attn = res/(den+eps) -> bf16 BLD ----------------
__global__ __launch_bounds__(256) void k_res(const unsigned short* __restrict__ qfb,
                                             const float* __restrict__ vk,
                                             unsigned short* __restrict__ attnb) {
  const int bh = blockIdx.x >> 5;
  const int lt = (blockIdx.x & 31) << 7;
  const int b = bh >> 4, h = bh & 15;
  const int t = threadIdx.x;
  const int wave = t >> 6, lane = t & 63;
  __shared__ unsigned short Aq[128 * 64];
  __shared__ unsigned short Bv[64 * 64];
  __shared__ float vkD[64];
  __shared__ float invden[128];

  const unsigned short* Ag = qfb + ((size_t)bh * 4096 + lt) * 64;
#pragma unroll
  for (int s = 0; s < 4; ++s)
    stage16(Ag + wave * 2048 + s * 512 + lane * 8, Aq + wave * 2048 + s * 512, lane);

  const float* vsrc = vk + (size_t)bh * 65 * 64;
  {
    int base = t * 16;
#pragma unroll
    for (int c = 0; c < 4; ++c) {
      float4 f = *reinterpret_cast<const float4*>(vsrc + base + c * 4);
      ushort4 o = { f2bf(f.x), f2bf(f.y), f2bf(f.z), f2bf(f.w) };
      *reinterpret_cast<ushort4*>(Bv + base + c * 4) = o;
    }
  }
  if (t < 64) vkD[t] = vsrc[64 * 64 + t];
  __syncthreads();

  f32x4 acc[2][4] = {};
  const int quad = lane >> 4, m16 = lane & 15;
#pragma unroll
  for (int step = 0; step < 2; ++step) {
    bf16x8 fa[2], fb[4];
#pragma unroll
    for (int i = 0; i < 2; ++i)
      fa[i] = *reinterpret_cast<const bf16x8*>(Aq + (wave * 32 + i * 16 + m16) * 64 +
                                               step * 32 + quad * 8);
#pragma unroll
    for (int j = 0; j < 4; ++j)
      fb[j] = *reinterpret_cast<const bf16x8*>(Bv + (j * 16 + m16) * 64 +
                                               step * 32 + quad * 8);
#pragma unroll
    for (int i = 0; i < 2; ++i)
#pragma unroll
      for (int j = 0; j < 4; ++j)
        acc[i][j] = __builtin_amdgcn_mfma_f32_16x16x32_bf16(fa[i], fb[j], acc[i][j], 0, 0, 0);
  }

  {
    const unsigned short* qr = Aq + (t >> 1) * 64 + (t & 1) * 32;
    const float* vd = vkD + (t & 1) * 32;
    float ds = 0.f;
#pragma unroll
    for (int c = 0; c < 4; ++c) {
      bf16x8 qv = *reinterpret_cast<const bf16x8*>(qr + c * 8);
#pragma unroll
      for (int j = 0; j < 8; ++j)
        ds += bf2f((unsigned short)qv[j]) * vd[c * 8 + j];
    }
    ds += __shfl_xor(ds, 1, 64);
    if ((t & 1) == 0) invden[t >> 1] = 1.0f / (ds + EPS_LIN);
  }
  __syncthreads();

#pragma unroll
  for (int i = 0; i < 2; ++i) {
#pragma unroll
    for (int r = 0; r < 4; ++r) {
      int row = wave * 32 + i * 16 + quad * 4 + r;
      float inv = invden[row];
      unsigned short* dst = attnb + ((size_t)(b * 4096 + lt + row)) * 1024 + h * 64;
#pragma unroll
      for (int j = 0; j < 4; ++j)
        dst[j * 16 + m16] = f2bf(acc[i][j][r] * inv);
    }
  }
}

// ---------------- final rmsnorm (R5: wave-per-row, no barriers) ----------------
__global__ __launch_bounds__(256) void k_outnorm(const unsigned short* __restrict__ preb,
                                                 const float* __restrict__ gout,
                                                 float* __restrict__ out) {
  const int row = (blockIdx.x << 2) + (threadIdx.x >> 6);
  const int lane = threadIdx.x & 63;
  const unsigned short* src = preb + (size_t)row * 1024;
  float* drow = out + (size_t)row * 1024;
  float v[16];
  float ss = 0.f;
#pragma unroll
  for (int c = 0; c < 4; ++c) {
    int d = c * 256 + lane * 4;
    ushort4 u = *reinterpret_cast<const ushort4*>(src + d);
    float a0 = bf2f(u.x), a1 = bf2f(u.y), a2 = bf2f(u.z), a3 = bf2f(u.w);
    v[c * 4 + 0] = a0; v[c * 4 + 1] = a1; v[c * 4 + 2] = a2; v[c * 4 + 3] = a3;
    ss += a0 * a0 + a1 * a1 + a2 * a2 + a3 * a3;
  }
#pragma unroll
  for (int off = 1; off < 64; off <<= 1) ss += __shfl_xor(ss, off, 64);
  const float sc = rsqrtf(ss * (1.0f / 1024.0f) + RMS_EPS);
#pragma unroll
  for (int c = 0; c < 4; ++c) {
    int d = c * 256 + lane * 4;
    float4 o = { v[c * 4 + 0] * sc * gout[d], v[c * 4 + 1] * sc * gout[d + 1],
                 v[c * 4 + 2] * sc * gout[d + 2], v[c * 4 + 3] * sc * gout[d + 3] };
    *reinterpret_cast<float4*>(drow + d) = o;
  }
}

// ---------------- workspace layout (bytes) ----------------
#define OFF_XB     0ull
#define OFF_WQKVB  33554432ull
#define OFF_WOUTB  39845888ull
#define OFF_QB     41943040ull
#define OFF_KB     75497472ull
#define OFF_VB     109051904ull
#define OFF_QFB    142606336ull
#define OFF_KFB    176160768ull
#define OFF_VK     209715200ull
#define OFF_ATTNB  210780160ull
#define OFF_COST   244334592ull
#define OFF_SINT   244858880ull
#define WS_NEEDED  245383168ull
// preb (bf16, 32MB) aliases OFF_QB (qb dead by then)

extern "C" void kernel_launch(void* const* d_in, const int* in_sizes, int n_in,
                              void* d_out, int out_size, void* d_ws, size_t ws_size,
                              hipStream_t stream) {
  const float* x    = (const float*)d_in[0];
  const float* Wqkv = (const float*)d_in[1];
  const float* bqkv = (const float*)d_in[2];
  const float* gq   = (const float*)d_in[3];
  const float* gk   = (const float*)d_in[4];
  const float* Wout = (const float*)d_in[5];
  const float* bout = (const float*)d_in[6];
  const float* gout = (const float*)d_in[7];

  if (ws_size < WS_NEEDED) return;

  char* ws = (char*)d_ws;
  unsigned short* xb    = (unsigned short*)(ws + OFF_XB);
  unsigned short* wqkvb = (unsigned short*)(ws + OFF_WQKVB);
  unsigned short* woutb = (unsigned short*)(ws + OFF_WOUTB);
  unsigned short* qb    = (unsigned short*)(ws + OFF_QB);
  unsigned short* kb    = (unsigned short*)(ws + OFF_KB);
  unsigned short* vb    = (unsigned short*)(ws + OFF_VB);
  unsigned short* qfb   = (unsigned short*)(ws + OFF_QFB);
  unsigned short* kfb   = (unsigned short*)(ws + OFF_KFB);
  float*          vkbuf = (float*)(ws + OFF_VK);
  unsigned short* attnb = (unsigned short*)(ws + OFF_ATTNB);
  float*          cosT  = (float*)(ws + OFF_COST);
  float*          sinT  = (float*)(ws + OFF_SINT);
  unsigned short* preb  = (unsigned short*)(ws + OFF_QB);  // alias

  // fused init: conversions + rope table + vkbuf zero (1 launch)
  k_init<<<21252, 256, 0, stream>>>(x, Wqkv, Wout, xb, wqkvb, woutb, cosT, sinT, vkbuf);

  // QKV gemm: M=16384 N=3072 K=1024
  k_gemm_bt<<<128 * 24, 256, 0, stream>>>(xb, wqkvb, bqkv, 16384, 3072, 1024, 0,
                                          qb, kb, vb, nullptr);
  k_qknorm<<<8192, 256, 0, stream>>>(qb, kb, gq, gk, cosT, sinT, qfb, kfb);

  k_vk<<<1024, 256, 0, stream>>>(vb, kfb, vkbuf);
  k_res<<<2048, 256, 0, stream>>>(qfb, vkbuf, attnb);

  // out gemm: M=16384 N=1024 K=1024 -> preb (bf16, aliases qb region)
  k_gemm_bt<<<128 * 8, 256, 0, stream>>>(attnb, woutb, bout, 16384, 1024, 1024, 1,
                                         nullptr, nullptr, nullptr, preb);
  k_outnorm<<<4096, 256, 0, stream>>>(preb, gout, (float*)d_out);
}